// Round 3
// baseline (2719.752 us; speedup 1.0000x reference)
//
#include <hip/hip_runtime.h>

typedef unsigned short u16;
typedef unsigned int u32;
typedef __attribute__((ext_vector_type(8))) __bf16 bf16x8;
typedef __attribute__((ext_vector_type(4))) float f32x4;

#define B_ 64
#define S_ 256
#define OBS_ 96
#define ACT_ 29
#define D_ 512
#define H_ 8
#define L_ 8
#define FF_ 2048
#define HD_ 64
#define NTOK (B_ * S_)   // 16384
#define QKV3 (3 * D_)    // 1536

__device__ __forceinline__ u16 f2bf(float f) {
    u32 u = __float_as_uint(f);
    u += 0x7FFFu + ((u >> 16) & 1u);
    return (u16)(u >> 16);
}
__device__ __forceinline__ float bf2f(u16 h) {
    return __uint_as_float(((u32)h) << 16);
}
// tanh-form GELU: max |err| vs exact erf-GELU ~3e-4 (below bf16 noise)
__device__ __forceinline__ float gelu_f(float x) {
    float z = 0.7978845608028654f * x * (1.0f + 0.044715f * x * x);
    float u = __expf(-2.0f * fabsf(z));
    float th = (1.0f - u) / (1.0f + u);
    th = copysignf(th, z);
    return 0.5f * x * (1.0f + th);
}
// async global->LDS, 16B per lane. LDS dest is wave-uniform base + lane*16.
__device__ __forceinline__ void gld_lds16(const u16* g, u16* l) {
    __builtin_amdgcn_global_load_lds(
        (const __attribute__((address_space(1))) unsigned int*)g,
        (__attribute__((address_space(3))) unsigned int*)l, 16, 0, 0);
}

// ---------------------------------------------------------------------------
// Transpose + downcast: src fp32 [z][K][N] -> dst bf16 [z][N][K] (strided)
// ---------------------------------------------------------------------------
__global__ __launch_bounds__(256) void transpose_bf16_kernel(
    const float* __restrict__ src, u16* __restrict__ dst, int K, int N,
    size_t srcStride, size_t dstStride)
{
    __shared__ float tile[32][33];
    int n0 = blockIdx.x * 32, k0 = blockIdx.y * 32;
    const float* s = src + (size_t)blockIdx.z * srcStride;
    u16* d = dst + (size_t)blockIdx.z * dstStride;
    int tx = threadIdx.x, ty = threadIdx.y;   // block (32,8)
    for (int i = 0; i < 32; i += 8)
        tile[ty + i][tx] = s[(size_t)(k0 + ty + i) * N + n0 + tx];
    __syncthreads();
    for (int i = 0; i < 32; i += 8)
        d[(size_t)(n0 + ty + i) * K + k0 + tx] = f2bf(tile[tx][ty + i]);
}

__global__ __launch_bounds__(256) void concat_bias_kernel(
    const float* __restrict__ bq, const float* __restrict__ bk,
    const float* __restrict__ bv, float* __restrict__ dst)
{
    int i = blockIdx.x * 256 + threadIdx.x;      // over L*1536
    int l = i / QKV3, r = i - l * QKV3;
    float v;
    if (r < D_)            v = bq[l * D_ + r];
    else if (r < 2 * D_)   v = bk[l * D_ + r - D_];
    else                   v = bv[l * D_ + r - 2 * D_];
    dst[i] = v;
}

// ---------------------------------------------------------------------------
// Input projection GEMM (fp32): outp[M][512] = obs[M][96] @ Win[96][512] + b
// ---------------------------------------------------------------------------
__global__ __launch_bounds__(256) void in_gemm_kernel(
    const float* __restrict__ obs, const float* __restrict__ Win,
    const float* __restrict__ b_in, float* __restrict__ outp)
{
    __shared__ float As[OBS_][68];
    __shared__ float Bs[OBS_][68];
    int m0 = blockIdx.y * 64, n0 = blockIdx.x * 64;
    int t = threadIdx.x;
    #pragma unroll
    for (int i = 0; i < 24; i++) {
        int idx = i * 256 + t;
        int m = idx / OBS_, kk = idx - m * OBS_;
        As[kk][m] = obs[(size_t)(m0 + m) * OBS_ + kk];
    }
    #pragma unroll
    for (int i = 0; i < 24; i++) {
        int idx = i * 256 + t;
        int kk = idx >> 6, n = idx & 63;
        Bs[kk][n] = Win[(size_t)kk * D_ + n0 + n];
    }
    __syncthreads();
    int tm = t >> 4, tn = t & 15;
    float acc[4][4] = {};
    for (int kk = 0; kk < OBS_; kk++) {
        float4 a = *(const float4*)&As[kk][tm * 4];
        float4 b = *(const float4*)&Bs[kk][tn * 4];
        const float av[4] = {a.x, a.y, a.z, a.w};
        const float bv[4] = {b.x, b.y, b.z, b.w};
        #pragma unroll
        for (int r = 0; r < 4; r++)
            #pragma unroll
            for (int c = 0; c < 4; c++) acc[r][c] += av[r] * bv[c];
    }
    #pragma unroll
    for (int r = 0; r < 4; r++)
        #pragma unroll
        for (int c = 0; c < 4; c++) {
            int col = n0 + tn * 4 + c;
            outp[(size_t)(m0 + tm * 4 + r) * D_ + col] = acc[r][c] + b_in[col];
        }
}

// ---------------------------------------------------------------------------
// GEMM: C[M][N] = A[M][K] @ BT[N][K] + bias (bf16 in, LDS chunk-swizzled)
// EPI: 0 = bf16 out, 1 = bf16+GELU, 2 = fp32 out
// SPLITK: gridDim.z==2; z=0 -> C (+bias), z=1 -> C2 (no bias). kLen per slice.
// ---------------------------------------------------------------------------
template <int EPI, bool SPLITK>
__global__ __launch_bounds__(256) void gemm_bt_kernel(
    const u16* __restrict__ A, const u16* __restrict__ BT,
    const float* __restrict__ bias, void* __restrict__ C,
    float* __restrict__ C2, int M, int N, int K, int kLen)
{
    __shared__ __align__(16) u16 As[128 * 32];
    __shared__ __align__(16) u16 Bs[128 * 32];
    int m0 = blockIdx.y * 128, n0 = blockIdx.x * 128;
    int z = SPLITK ? blockIdx.z : 0;
    int kStart = z * kLen;
    int t = threadIdx.x;
    int lane = t & 63, w = t >> 6;
    int wm = w >> 1, wn = w & 1;
    int l15 = lane & 15, quad = lane >> 4;

    // staging pointers (hoisted): chunk ids c0a/c0b -> (row, swizzled col)
    int c0a = w * 128 + lane;
    int c0b = c0a + 64;
    int rA0 = c0a >> 2, cA0 = (c0a & 3) ^ ((rA0 >> 1) & 3);
    int rA1 = c0b >> 2, cA1 = (c0b & 3) ^ ((rA1 >> 1) & 3);
    const u16* gA0 = A + (size_t)(m0 + rA0) * K + kStart + cA0 * 8;
    const u16* gA1 = A + (size_t)(m0 + rA1) * K + kStart + cA1 * 8;
    const u16* gB0 = BT + (size_t)(n0 + rA0) * K + kStart + cA0 * 8;
    const u16* gB1 = BT + (size_t)(n0 + rA1) * K + kStart + cA1 * 8;
    u16* lA0 = &As[c0a * 8]; u16* lA1 = &As[c0b * 8];
    u16* lB0 = &Bs[c0a * 8]; u16* lB1 = &Bs[c0b * 8];

    // fragment read offsets (swizzled), hoisted
    int aoff[4], boff[4];
    #pragma unroll
    for (int mi = 0; mi < 4; mi++) {
        int row = wm * 64 + mi * 16 + l15;
        aoff[mi] = row * 32 + (quad ^ ((row >> 1) & 3)) * 8;
    }
    #pragma unroll
    for (int ni = 0; ni < 4; ni++) {
        int row = wn * 64 + ni * 16 + l15;
        boff[ni] = row * 32 + (quad ^ ((row >> 1) & 3)) * 8;
    }

    f32x4 acc[4][4];
    f32x4 zero = {0.f, 0.f, 0.f, 0.f};
    #pragma unroll
    for (int mi = 0; mi < 4; mi++)
        #pragma unroll
        for (int ni = 0; ni < 4; ni++) acc[mi][ni] = zero;

    for (int kk = 0; kk < kLen; kk += 32) {
        __syncthreads();
        gld_lds16(gA0, lA0); gld_lds16(gA1, lA1);
        gld_lds16(gB0, lB0); gld_lds16(gB1, lB1);
        gA0 += 32; gA1 += 32; gB0 += 32; gB1 += 32;
        __syncthreads();
        bf16x8 a[4], b[4];
        #pragma unroll
        for (int mi = 0; mi < 4; mi++) a[mi] = *(const bf16x8*)&As[aoff[mi]];
        #pragma unroll
        for (int ni = 0; ni < 4; ni++) b[ni] = *(const bf16x8*)&Bs[boff[ni]];
        #pragma unroll
        for (int mi = 0; mi < 4; mi++)
            #pragma unroll
            for (int ni = 0; ni < 4; ni++)
                acc[mi][ni] = __builtin_amdgcn_mfma_f32_16x16x32_bf16(
                    a[mi], b[ni], acc[mi][ni], 0, 0, 0);
    }

    bool partial = SPLITK && (z == 1);
    #pragma unroll
    for (int ni = 0; ni < 4; ni++) {
        int col = n0 + wn * 64 + ni * 16 + l15;
        float bv = partial ? 0.f : bias[col];
        #pragma unroll
        for (int mi = 0; mi < 4; mi++) {
            int rbase = m0 + wm * 64 + mi * 16 + quad * 4;
            f32x4 v = acc[mi][ni];
            #pragma unroll
            for (int r = 0; r < 4; r++) {
                float y = v[r] + bv;
                size_t idx = (size_t)(rbase + r) * N + col;
                if (partial)         C2[idx] = y;
                else if (EPI == 2)   ((float*)C)[idx] = y;
                else if (EPI == 1)   ((u16*)C)[idx] = f2bf(gelu_f(y));
                else                 ((u16*)C)[idx] = f2bf(y);
            }
        }
    }
}

// ---------------------------------------------------------------------------
// Attention on fused qkv [NTOK][1536]. Block = (b,h,64 q rows). LDS swizzled.
// ---------------------------------------------------------------------------
__global__ __launch_bounds__(256) void attn_kernel(
    const u16* __restrict__ qkv, u16* __restrict__ o)
{
    __shared__ __align__(16) u16 kvs[S_ * HD_];      // 32 KB: K rows, then V^T
    __shared__ __align__(16) u16 P[4 * 16 * S_];     // 32 KB: per-wave probs
    int bx = blockIdx.x;
    int qc = bx & 3;
    int h = (bx >> 2) & 7;
    int b = bx >> 5;
    int t = threadIdx.x;
    int lane = t & 63, w = t >> 6;
    int l15 = lane & 15, quad = lane >> 4;
    size_t rowb = (size_t)b * S_;

    // stage K rows, chunk-swizzled: row t, chunk j at slot j^(t&7)
    {
        const u16* src = qkv + (rowb + t) * QKV3 + D_ + h * HD_;
        int sw = t & 7;
        #pragma unroll
        for (int j = 0; j < 8; j++)
            *(uint4*)&kvs[t * HD_ + ((j ^ sw) * 8)] = *(const uint4*)(src + j * 8);
    }
    bf16x8 aQ[2];
    {
        int qrow = qc * 64 + w * 16 + l15;
        const u16* src = qkv + (rowb + qrow) * QKV3 + h * HD_ + quad * 8;
        aQ[0] = *(const bf16x8*)(src);
        aQ[1] = *(const bf16x8*)(src + 32);
    }
    __syncthreads();

    // phase 1: S = Q K^T  (wave computes 16 x 256)
    f32x4 sc[16];
    #pragma unroll
    for (int nc = 0; nc < 16; nc++) {
        f32x4 acc = {0.f, 0.f, 0.f, 0.f};
        int row = nc * 16 + l15;
        int s0 = quad ^ (row & 7);
        bf16x8 b0 = *(const bf16x8*)&kvs[row * HD_ + s0 * 8];
        bf16x8 b1 = *(const bf16x8*)&kvs[row * HD_ + (s0 ^ 4) * 8];
        acc = __builtin_amdgcn_mfma_f32_16x16x32_bf16(aQ[0], b0, acc, 0, 0, 0);
        acc = __builtin_amdgcn_mfma_f32_16x16x32_bf16(aQ[1], b1, acc, 0, 0, 0);
        sc[nc] = acc;
    }
    const float scale = 0.125f;  // 1/sqrt(64)
    float rmax[4], rinv[4];
    #pragma unroll
    for (int r = 0; r < 4; r++) {
        float mx = -1e30f;
        #pragma unroll
        for (int nc = 0; nc < 16; nc++) mx = fmaxf(mx, sc[nc][r]);
        for (int off = 1; off < 16; off <<= 1) mx = fmaxf(mx, __shfl_xor(mx, off));
        rmax[r] = mx * scale;
    }
    #pragma unroll
    for (int r = 0; r < 4; r++) {
        float sum = 0.f;
        #pragma unroll
        for (int nc = 0; nc < 16; nc++) {
            float p = __expf(sc[nc][r] * scale - rmax[r]);
            sc[nc][r] = p;
            sum += p;
        }
        for (int off = 1; off < 16; off <<= 1) sum += __shfl_xor(sum, off);
        rinv[r] = 1.0f / sum;
    }
    // P store (bf16), chunk-swizzled per row
    #pragma unroll
    for (int nc = 0; nc < 16; nc++)
        #pragma unroll
        for (int r = 0; r < 4; r++) {
            int prow = quad * 4 + r;
            int col = nc * 16 + l15;
            int slot = (col >> 3) ^ (prow & 7);
            P[w * 4096 + prow * 256 + slot * 8 + (col & 7)] =
                f2bf(sc[nc][r] * rinv[r]);
        }
    __syncthreads();  // all waves done reading K + writing P

    // stage V^T[64 d][256 s], chunk-swizzled: row d, chunk c at slot c^(d&7)
    {
        const u16* src = qkv + (rowb + t) * QKV3 + 2 * D_ + h * HD_;
        int chunkc = t >> 3, bytec = t & 7;
        #pragma unroll
        for (int dj = 0; dj < 8; dj++) {
            uint4 x = *(const uint4*)(src + dj * 8);
            const u16* xs = (const u16*)&x;
            #pragma unroll
            for (int i = 0; i < 8; i++) {
                int vrow = dj * 8 + i;
                kvs[vrow * 256 + ((chunkc ^ (vrow & 7)) * 8) + bytec] = xs[i];
            }
        }
    }
    __syncthreads();

    // phase 2: O = P @ V   (wave: 16 x 64)
    f32x4 accO[4];
    f32x4 zero = {0.f, 0.f, 0.f, 0.f};
    #pragma unroll
    for (int nt = 0; nt < 4; nt++) accO[nt] = zero;
    for (int ks = 0; ks < 8; ks++) {
        int ch = ks * 4 + quad;
        bf16x8 aP = *(const bf16x8*)&P[w * 4096 + l15 * 256 + ((ch ^ (l15 & 7)) * 8)];
        #pragma unroll
        for (int nt = 0; nt < 4; nt++) {
            int vrow = nt * 16 + l15;
            bf16x8 bV = *(const bf16x8*)&kvs[vrow * 256 + ((ch ^ (vrow & 7)) * 8)];
            accO[nt] = __builtin_amdgcn_mfma_f32_16x16x32_bf16(aP, bV, accO[nt], 0, 0, 0);
        }
    }
    #pragma unroll
    for (int nt = 0; nt < 4; nt++)
        #pragma unroll
        for (int r = 0; r < 4; r++) {
            int orow = qc * 64 + w * 16 + quad * 4 + r;
            o[(rowb + orow) * D_ + h * HD_ + nt * 16 + l15] = f2bf(accO[nt][r]);
        }
}

// ---------------------------------------------------------------------------
// LayerNorm: out = LN(in [+ in2] [+ res]) * g + b, optional GELU / PE.
// ---------------------------------------------------------------------------
template <int WIDTH, bool RES, bool GELU, bool PE, bool SUM2>
__global__ __launch_bounds__(WIDTH) void ln_kernel(
    const float* __restrict__ in, const float* __restrict__ in2,
    const u16* __restrict__ res,
    const float* __restrict__ g, const float* __restrict__ b,
    u16* __restrict__ out)
{
    __shared__ float rs[8], rq[8];
    int row = blockIdx.x;
    int t = threadIdx.x;
    size_t base = (size_t)row * WIDTH;
    float v = in[base + t];
    if (SUM2) v += in2[base + t];
    if (RES) v += bf2f(res[base + t]);
    float sm = v, sq = v * v;
    for (int off = 32; off; off >>= 1) {
        sm += __shfl_xor(sm, off);
        sq += __shfl_xor(sq, off);
    }
    constexpr int NW = WIDTH / 64;
    if ((t & 63) == 0) { rs[t >> 6] = sm; rq[t >> 6] = sq; }
    __syncthreads();
    float ts = 0.f, tq = 0.f;
    #pragma unroll
    for (int i = 0; i < NW; i++) { ts += rs[i]; tq += rq[i]; }
    float mean = ts / (float)WIDTH;
    float var = tq / (float)WIDTH - mean * mean;
    float rstd = rsqrtf(var + 1e-5f);
    float y = (v - mean) * rstd * g[t] + b[t];
    if (GELU) y = gelu_f(y);
    if (PE) {
        const float c = -9.210340371976184f / (float)D_;  // -ln(10000)/D
        int s = row & (S_ - 1);
        int i2 = t >> 1;
        float ang = (float)s * __expf((float)(2 * i2) * c);
        y += (t & 1) ? __cosf(ang) : __sinf(ang);
    }
    out[base + t] = f2bf(y);
}

// ---------------------------------------------------------------------------
// Head: out = tanh(y2 @ Wp3 + bp3) * scale + bias. 8 rows x 32 cols per block.
// ---------------------------------------------------------------------------
__global__ __launch_bounds__(256) void head_kernel(
    const u16* __restrict__ y2, const float* __restrict__ W,
    const float* __restrict__ bias, const float* __restrict__ scl,
    const float* __restrict__ bs, float* __restrict__ out)
{
    __shared__ float Ws[128 * ACT_];
    __shared__ u16 Ys[8 * 128];
    int t = threadIdx.x;
    for (int i = t; i < 128 * ACT_; i += 256) Ws[i] = W[i];
    int r0 = blockIdx.x * 8;
    for (int i = t; i < 8 * 128; i += 256) Ys[i] = y2[(size_t)r0 * 128 + i];
    __syncthreads();
    int lr = t >> 5, c = t & 31;
    if (c < ACT_) {
        float acc = bias[c];
        for (int kk = 0; kk < 128; kk++)
            acc += bf2f(Ys[lr * 128 + kk]) * Ws[kk * ACT_ + c];
        float y = tanhf(acc);
        out[(size_t)(r0 + lr) * ACT_ + c] = y * scl[c] + bs[c];
    }
}

// ---------------------------------------------------------------------------
extern "C" void kernel_launch(void* const* d_in, const int* in_sizes, int n_in,
                              void* d_out, int out_size, void* d_ws, size_t ws_size,
                              hipStream_t stream)
{
    const float* obs   = (const float*)d_in[0];
    const float* W_in  = (const float*)d_in[1];
    const float* b_in  = (const float*)d_in[2];
    const float* g_in  = (const float*)d_in[3];
    const float* be_in = (const float*)d_in[4];
    const float* Wq  = (const float*)d_in[5];
    const float* bq  = (const float*)d_in[6];
    const float* Wk  = (const float*)d_in[7];
    const float* bk  = (const float*)d_in[8];
    const float* Wv  = (const float*)d_in[9];
    const float* bv  = (const float*)d_in[10];
    const float* Wo  = (const float*)d_in[11];
    const float* bo  = (const float*)d_in[12];
    const float* g1  = (const float*)d_in[13];
    const float* be1 = (const float*)d_in[14];
    const float* W1  = (const float*)d_in[15];
    const float* b1  = (const float*)d_in[16];
    const float* W2  = (const float*)d_in[17];
    const float* b2  = (const float*)d_in[18];
    const float* g2  = (const float*)d_in[19];
    const float* be2 = (const float*)d_in[20];
    const float* Wp1  = (const float*)d_in[21];
    const float* bp1  = (const float*)d_in[22];
    const float* gp1  = (const float*)d_in[23];
    const float* bep1 = (const float*)d_in[24];
    const float* Wp2  = (const float*)d_in[25];
    const float* bp2  = (const float*)d_in[26];
    const float* gp2  = (const float*)d_in[27];
    const float* bep2 = (const float*)d_in[28];
    const float* Wp3  = (const float*)d_in[29];
    const float* bp3  = (const float*)d_in[30];
    const float* ascl = (const float*)d_in[31];
    const float* abias = (const float*)d_in[32];

    char* ws = (char*)d_ws;
    size_t off = 0;
    auto alloc = [&](size_t bytes) {
        void* p = ws + off;
        off += (bytes + 255) & ~(size_t)255;
        return p;
    };
    u16* WQKVT = (u16*)alloc((size_t)L_ * QKV3 * D_ * 2);     // 12.6 MB
    u16* WOT   = (u16*)alloc((size_t)L_ * D_ * D_ * 2);       // 4 MB
    u16* W1T   = (u16*)alloc((size_t)L_ * D_ * FF_ * 2);      // 16 MB
    u16* W2T   = (u16*)alloc((size_t)L_ * FF_ * D_ * 2);      // 16 MB
    u16* WP1T  = (u16*)alloc((size_t)D_ * (D_ / 2) * 2);
    u16* WP2T  = (u16*)alloc((size_t)(D_ / 2) * (D_ / 4) * 2);
    float* bqkv = (float*)alloc((size_t)L_ * QKV3 * 4);
    u16* x_bf = (u16*)alloc((size_t)NTOK * D_ * 2);           // 16 MB
    float* tmp = (float*)alloc((size_t)NTOK * D_ * 4);        // 32 MB
    char* regionA = (char*)alloc((size_t)NTOK * FF_ * 2);     // 64 MB
    size_t base_need = off;
    float* tmp2 = (float*)(ws + base_need);                   // +32 MB if fits
    bool split = (ws_size >= base_need + (size_t)NTOK * D_ * 4);
    (void)in_sizes; (void)n_in; (void)out_size;

    u16* qkvbuf = (u16*)(regionA);                            // 48 MB
    u16* obuf = (u16*)(regionA + (size_t)NTOK * QKV3 * 2);    // 16 MB
    u16* hbuf = (u16*)(regionA);                              // 64 MB (aliases)
    // head-phase aliases (regionA free then)
    float* p1out = tmp;                                       // [NTOK][256] f32
    float* p1part = tmp2;
    u16* y1_bf = (u16*)(regionA);                             // 8 MB
    float* p2out = tmp;                                       // [NTOK][128] f32
    float* p2part = tmp2;
    u16* y2_bf = (u16*)(regionA + (32u << 20));               // 4 MB

    dim3 tb(32, 8);
    size_t DD = (size_t)D_ * D_;
    transpose_bf16_kernel<<<dim3(16, 16, L_), tb, 0, stream>>>(
        Wq, WQKVT, D_, D_, DD, (size_t)QKV3 * D_);
    transpose_bf16_kernel<<<dim3(16, 16, L_), tb, 0, stream>>>(
        Wk, WQKVT + DD, D_, D_, DD, (size_t)QKV3 * D_);
    transpose_bf16_kernel<<<dim3(16, 16, L_), tb, 0, stream>>>(
        Wv, WQKVT + 2 * DD, D_, D_, DD, (size_t)QKV3 * D_);
    transpose_bf16_kernel<<<dim3(16, 16, L_), tb, 0, stream>>>(
        Wo, WOT, D_, D_, DD, DD);
    transpose_bf16_kernel<<<dim3(64, 16, L_), tb, 0, stream>>>(
        W1, W1T, D_, FF_, (size_t)D_ * FF_, (size_t)D_ * FF_);
    transpose_bf16_kernel<<<dim3(16, 64, L_), tb, 0, stream>>>(
        W2, W2T, FF_, D_, (size_t)D_ * FF_, (size_t)D_ * FF_);
    transpose_bf16_kernel<<<dim3(8, 16, 1), tb, 0, stream>>>(
        Wp1, WP1T, D_, D_ / 2, 0, 0);
    transpose_bf16_kernel<<<dim3(4, 8, 1), tb, 0, stream>>>(
        Wp2, WP2T, D_ / 2, D_ / 4, 0, 0);
    concat_bias_kernel<<<L_ * QKV3 / 256, 256, 0, stream>>>(bq, bk, bv, bqkv);

    in_gemm_kernel<<<dim3(D_ / 64, NTOK / 64), 256, 0, stream>>>(
        obs, W_in, b_in, tmp);
    ln_kernel<D_, false, true, true, false><<<NTOK, D_, 0, stream>>>(
        tmp, nullptr, nullptr, g_in, be_in, x_bf);

    const int MG = NTOK / 128;  // 128
    for (int l = 0; l < L_; l++) {
        const u16* wqkvt = WQKVT + (size_t)l * QKV3 * D_;
        const u16* wot = WOT + (size_t)l * DD;
        const u16* w1t = W1T + (size_t)l * D_ * FF_;
        const u16* w2t = W2T + (size_t)l * FF_ * D_;

        gemm_bt_kernel<0, false><<<dim3(QKV3 / 128, MG), 256, 0, stream>>>(
            x_bf, wqkvt, bqkv + l * QKV3, qkvbuf, nullptr, NTOK, QKV3, D_, D_);
        attn_kernel<<<B_ * H_ * (S_ / 64), 256, 0, stream>>>(qkvbuf, obuf);
        if (split) {
            gemm_bt_kernel<2, true><<<dim3(D_ / 128, MG, 2), 256, 0, stream>>>(
                obuf, wot, bo + l * D_, tmp, tmp2, NTOK, D_, D_, D_ / 2);
            ln_kernel<D_, true, false, false, true><<<NTOK, D_, 0, stream>>>(
                tmp, tmp2, x_bf, g1 + l * D_, be1 + l * D_, x_bf);
        } else {
            gemm_bt_kernel<2, false><<<dim3(D_ / 128, MG), 256, 0, stream>>>(
                obuf, wot, bo + l * D_, tmp, nullptr, NTOK, D_, D_, D_);
            ln_kernel<D_, true, false, false, false><<<NTOK, D_, 0, stream>>>(
                tmp, nullptr, x_bf, g1 + l * D_, be1 + l * D_, x_bf);
        }
        gemm_bt_kernel<1, false><<<dim3(FF_ / 128, MG), 256, 0, stream>>>(
            x_bf, w1t, b1 + l * FF_, hbuf, nullptr, NTOK, FF_, D_, D_);
        if (split) {
            gemm_bt_kernel<2, true><<<dim3(D_ / 128, MG, 2), 256, 0, stream>>>(
                hbuf, w2t, b2 + l * D_, tmp, tmp2, NTOK, D_, FF_, FF_ / 2);
            ln_kernel<D_, true, false, false, true><<<NTOK, D_, 0, stream>>>(
                tmp, tmp2, x_bf, g2 + l * D_, be2 + l * D_, x_bf);
        } else {
            gemm_bt_kernel<2, false><<<dim3(D_ / 128, MG), 256, 0, stream>>>(
                hbuf, w2t, b2 + l * D_, tmp, nullptr, NTOK, D_, FF_, FF_);
            ln_kernel<D_, true, false, false, false><<<NTOK, D_, 0, stream>>>(
                tmp, nullptr, x_bf, g2 + l * D_, be2 + l * D_, x_bf);
        }
    }

    // policy head
    if (split) {
        gemm_bt_kernel<2, true><<<dim3(2, MG, 2), 256, 0, stream>>>(
            x_bf, WP1T, bp1, p1out, p1part, NTOK, D_ / 2, D_, D_ / 2);
        ln_kernel<D_ / 2, false, true, false, true><<<NTOK, D_ / 2, 0, stream>>>(
            p1out, p1part, nullptr, gp1, bep1, y1_bf);
        gemm_bt_kernel<2, true><<<dim3(1, MG, 2), 256, 0, stream>>>(
            y1_bf, WP2T, bp2, p2out, p2part, NTOK, D_ / 4, D_ / 2, D_ / 4);
        ln_kernel<D_ / 4, false, true, false, true><<<NTOK, D_ / 4, 0, stream>>>(
            p2out, p2part, nullptr, gp2, bep2, y2_bf);
    } else {
        gemm_bt_kernel<2, false><<<dim3(2, MG), 256, 0, stream>>>(
            x_bf, WP1T, bp1, p1out, nullptr, NTOK, D_ / 2, D_, D_);
        ln_kernel<D_ / 2, false, true, false, false><<<NTOK, D_ / 2, 0, stream>>>(
            p1out, nullptr, nullptr, gp1, bep1, y1_bf);
        gemm_bt_kernel<2, false><<<dim3(1, MG), 256, 0, stream>>>(
            y1_bf, WP2T, bp2, p2out, nullptr, NTOK, D_ / 4, D_ / 2, D_ / 2);
        ln_kernel<D_ / 4, false, true, false, false><<<NTOK, D_ / 4, 0, stream>>>(
            p2out, nullptr, nullptr, gp2, bep2, y2_bf);
    }
    head_kernel<<<NTOK / 8, 256, 0, stream>>>(
        y2_bf, Wp3, bp3, ascl, abias, (float*)d_out);
}

// Round 5
// 2715.377 us; speedup vs baseline: 1.0016x; 1.0016x over previous
//
#include <hip/hip_runtime.h>

typedef unsigned short u16;
typedef unsigned int u32;
typedef __attribute__((ext_vector_type(8))) __bf16 bf16x8;
typedef __attribute__((ext_vector_type(4))) float f32x4;

#define B_ 64
#define S_ 256
#define OBS_ 96
#define ACT_ 29
#define D_ 512
#define H_ 8
#define L_ 8
#define FF_ 2048
#define HD_ 64
#define NTOK (B_ * S_)   // 16384
#define QKV3 (3 * D_)    // 1536

__device__ __forceinline__ u16 f2bf(float f) {
    u32 u = __float_as_uint(f);
    u += 0x7FFFu + ((u >> 16) & 1u);
    return (u16)(u >> 16);
}
__device__ __forceinline__ float bf2f(u16 h) {
    return __uint_as_float(((u32)h) << 16);
}
// 7-inst GELU: x*sigmoid(2z), z = 0.79788456(x+0.044715x^3), exp2/rcp form.
// Max |err| vs exact erf-GELU ~3e-4 (below bf16 noise).
__device__ __forceinline__ float gelu_f(float x) {
    const float k1 = 2.3022121f;    // 2*0.79788456*log2(e)
    const float k2 = 0.10294451f;   // k1*0.044715
    float x2 = x * x;
    float arg = x * __builtin_fmaf(x2, k2, k1);
    float e = exp2f(arg);
    float r = __builtin_amdgcn_rcpf(1.0f + e);
    return __builtin_fmaf(-x, r, x);
}
// async global->LDS, 16B per lane. LDS dest is wave-uniform base + lane*16.
__device__ __forceinline__ void gld_lds16(const u16* g, u16* l) {
    __builtin_amdgcn_global_load_lds(
        (const __attribute__((address_space(1))) unsigned int*)g,
        (__attribute__((address_space(3))) unsigned int*)l, 16, 0, 0);
}

// ---------------------------------------------------------------------------
// Transpose + downcast: src fp32 [z][K][N] -> dst bf16 [z][N][K] (strided)
// ---------------------------------------------------------------------------
__global__ __launch_bounds__(256) void transpose_bf16_kernel(
    const float* __restrict__ src, u16* __restrict__ dst, int K, int N,
    size_t srcStride, size_t dstStride)
{
    __shared__ float tile[32][33];
    int n0 = blockIdx.x * 32, k0 = blockIdx.y * 32;
    const float* s = src + (size_t)blockIdx.z * srcStride;
    u16* d = dst + (size_t)blockIdx.z * dstStride;
    int tx = threadIdx.x, ty = threadIdx.y;   // block (32,8)
    for (int i = 0; i < 32; i += 8)
        tile[ty + i][tx] = s[(size_t)(k0 + ty + i) * N + n0 + tx];
    __syncthreads();
    for (int i = 0; i < 32; i += 8)
        d[(size_t)(n0 + ty + i) * K + k0 + tx] = f2bf(tile[tx][ty + i]);
}

__global__ __launch_bounds__(256) void concat_bias_kernel(
    const float* __restrict__ bq, const float* __restrict__ bk,
    const float* __restrict__ bv, float* __restrict__ dst)
{
    int i = blockIdx.x * 256 + threadIdx.x;      // over L*1536
    int l = i / QKV3, r = i - l * QKV3;
    float v;
    if (r < D_)            v = bq[l * D_ + r];
    else if (r < 2 * D_)   v = bk[l * D_ + r - D_];
    else                   v = bv[l * D_ + r - 2 * D_];
    dst[i] = v;
}

// ---------------------------------------------------------------------------
// Input projection GEMM (fp32): outp[M][512] = obs[M][96] @ Win[96][512] + b
// ---------------------------------------------------------------------------
__global__ __launch_bounds__(256) void in_gemm_kernel(
    const float* __restrict__ obs, const float* __restrict__ Win,
    const float* __restrict__ b_in, float* __restrict__ outp)
{
    __shared__ float As[OBS_][68];
    __shared__ float Bs[OBS_][68];
    int m0 = blockIdx.y * 64, n0 = blockIdx.x * 64;
    int t = threadIdx.x;
    #pragma unroll
    for (int i = 0; i < 24; i++) {
        int idx = i * 256 + t;
        int m = idx / OBS_, kk = idx - m * OBS_;
        As[kk][m] = obs[(size_t)(m0 + m) * OBS_ + kk];
    }
    #pragma unroll
    for (int i = 0; i < 24; i++) {
        int idx = i * 256 + t;
        int kk = idx >> 6, n = idx & 63;
        Bs[kk][n] = Win[(size_t)kk * D_ + n0 + n];
    }
    __syncthreads();
    int tm = t >> 4, tn = t & 15;
    float acc[4][4] = {};
    for (int kk = 0; kk < OBS_; kk++) {
        float4 a = *(const float4*)&As[kk][tm * 4];
        float4 b = *(const float4*)&Bs[kk][tn * 4];
        const float av[4] = {a.x, a.y, a.z, a.w};
        const float bv[4] = {b.x, b.y, b.z, b.w};
        #pragma unroll
        for (int r = 0; r < 4; r++)
            #pragma unroll
            for (int c = 0; c < 4; c++) acc[r][c] += av[r] * bv[c];
    }
    #pragma unroll
    for (int r = 0; r < 4; r++)
        #pragma unroll
        for (int c = 0; c < 4; c++) {
            int col = n0 + tn * 4 + c;
            outp[(size_t)(m0 + tm * 4 + r) * D_ + col] = acc[r][c] + b_in[col];
        }
}

// ---------------------------------------------------------------------------
// GEMM: C[M][N] = A[M][K] @ BT[N][K] + bias (bf16 in, LDS chunk-swizzled)
// EPI: 0 = bf16 out, 1 = bf16+GELU, 2 = fp32 out
// TN: 128 or 64 (M-tile always 128; 4 waves, wave grid 2x2)
// SPLITK: gridDim.z==2; z=0 -> C (+bias), z=1 -> C2 (no bias). kLen per slice.
// ---------------------------------------------------------------------------
template <int EPI, int TN, bool SPLITK>
__global__ __launch_bounds__(256) void gemm_bt_kernel(
    const u16* __restrict__ A, const u16* __restrict__ BT,
    const float* __restrict__ bias, void* __restrict__ C,
    float* __restrict__ C2, int M, int N, int K, int kLen)
{
    constexpr int NI = TN / 32;               // acc tiles per wave in N
    __shared__ __align__(16) u16 As[128 * 32];
    __shared__ __align__(16) u16 Bs[TN * 32];
    int m0 = blockIdx.y * 128, n0 = blockIdx.x * TN;
    int z = SPLITK ? blockIdx.z : 0;
    int kStart = z * kLen;
    int t = threadIdx.x;
    int lane = t & 63, w = t >> 6;
    int wm = w >> 1, wn = w & 1;
    int l15 = lane & 15, quad = lane >> 4;

    // A staging: 512 chunks (16B each), 2 per thread
    int c0a = w * 128 + lane;
    int c0b = c0a + 64;
    int rA0 = c0a >> 2, cA0 = (c0a & 3) ^ ((rA0 >> 1) & 3);
    int rA1 = c0b >> 2, cA1 = (c0b & 3) ^ ((rA1 >> 1) & 3);
    const u16* gA0 = A + (size_t)(m0 + rA0) * K + kStart + cA0 * 8;
    const u16* gA1 = A + (size_t)(m0 + rA1) * K + kStart + cA1 * 8;
    u16* lA0 = &As[c0a * 8]; u16* lA1 = &As[c0b * 8];
    // B staging: TN*4 chunks (2 per thread if TN=128, 1 if TN=64)
    int cb0 = (TN == 128) ? c0a : (w * 64 + lane);
    int rB0 = cb0 >> 2, cB0 = (cb0 & 3) ^ ((rB0 >> 1) & 3);
    const u16* gB0 = BT + (size_t)(n0 + rB0) * K + kStart + cB0 * 8;
    u16* lB0 = &Bs[cb0 * 8];
    const u16* gB1 = nullptr; u16* lB1 = nullptr;
    if (TN == 128) {
        int cb1 = c0b;
        int rB1 = cb1 >> 2, cB1 = (cb1 & 3) ^ ((rB1 >> 1) & 3);
        gB1 = BT + (size_t)(n0 + rB1) * K + kStart + cB1 * 8;
        lB1 = &Bs[cb1 * 8];
    }

    // fragment read offsets (swizzled), hoisted
    int aoff[4], boff[NI];
    #pragma unroll
    for (int mi = 0; mi < 4; mi++) {
        int row = wm * 64 + mi * 16 + l15;
        aoff[mi] = row * 32 + (quad ^ ((row >> 1) & 3)) * 8;
    }
    #pragma unroll
    for (int ni = 0; ni < NI; ni++) {
        int row = wn * (TN / 2) + ni * 16 + l15;
        boff[ni] = row * 32 + (quad ^ ((row >> 1) & 3)) * 8;
    }

    f32x4 acc[4][NI];
    f32x4 zero = {0.f, 0.f, 0.f, 0.f};
    #pragma unroll
    for (int mi = 0; mi < 4; mi++)
        #pragma unroll
        for (int ni = 0; ni < NI; ni++) acc[mi][ni] = zero;

    for (int kk = 0; kk < kLen; kk += 32) {
        __syncthreads();
        gld_lds16(gA0, lA0); gld_lds16(gA1, lA1);
        gld_lds16(gB0, lB0);
        if (TN == 128) gld_lds16(gB1, lB1);
        gA0 += 32; gA1 += 32; gB0 += 32;
        if (TN == 128) gB1 += 32;
        __syncthreads();
        bf16x8 a[4], b[NI];
        #pragma unroll
        for (int mi = 0; mi < 4; mi++) a[mi] = *(const bf16x8*)&As[aoff[mi]];
        #pragma unroll
        for (int ni = 0; ni < NI; ni++) b[ni] = *(const bf16x8*)&Bs[boff[ni]];
        #pragma unroll
        for (int mi = 0; mi < 4; mi++)
            #pragma unroll
            for (int ni = 0; ni < NI; ni++)
                acc[mi][ni] = __builtin_amdgcn_mfma_f32_16x16x32_bf16(
                    a[mi], b[ni], acc[mi][ni], 0, 0, 0);
    }

    bool partial = SPLITK && (z == 1);
    #pragma unroll
    for (int ni = 0; ni < NI; ni++) {
        int col = n0 + wn * (TN / 2) + ni * 16 + l15;
        float bv = partial ? 0.f : bias[col];
        #pragma unroll
        for (int mi = 0; mi < 4; mi++) {
            int rbase = m0 + wm * 64 + mi * 16 + quad * 4;
            f32x4 v = acc[mi][ni];
            #pragma unroll
            for (int r = 0; r < 4; r++) {
                float y = v[r] + bv;
                size_t idx = (size_t)(rbase + r) * N + col;
                if (partial)         C2[idx] = y;
                else if (EPI == 2)   ((float*)C)[idx] = y;
                else if (EPI == 1)   ((u16*)C)[idx] = f2bf(gelu_f(y));
                else                 ((u16*)C)[idx] = f2bf(y);
            }
        }
    }
}

// ---------------------------------------------------------------------------
// Attention on fused qkv [NTOK][1536]. Block = (b,h,64 q rows). LDS swizzled.
// ---------------------------------------------------------------------------
__global__ __launch_bounds__(256) void attn_kernel(
    const u16* __restrict__ qkv, u16* __restrict__ o)
{
    __shared__ __align__(16) u16 kvs[S_ * HD_];      // 32 KB: K rows, then V^T
    __shared__ __align__(16) u16 P[4 * 16 * S_];     // 32 KB: per-wave probs
    int bx = blockIdx.x;
    int qc = bx & 3;
    int h = (bx >> 2) & 7;
    int b = bx >> 5;
    int t = threadIdx.x;
    int lane = t & 63, w = t >> 6;
    int l15 = lane & 15, quad = lane >> 4;
    size_t rowb = (size_t)b * S_;

    // stage K rows, chunk-swizzled: row t, chunk j at slot j^(t&7)
    {
        const u16* src = qkv + (rowb + t) * QKV3 + D_ + h * HD_;
        int sw = t & 7;
        #pragma unroll
        for (int j = 0; j < 8; j++)
            *(uint4*)&kvs[t * HD_ + ((j ^ sw) * 8)] = *(const uint4*)(src + j * 8);
    }
    bf16x8 aQ[2];
    {
        int qrow = qc * 64 + w * 16 + l15;
        const u16* src = qkv + (rowb + qrow) * QKV3 + h * HD_ + quad * 8;
        aQ[0] = *(const bf16x8*)(src);
        aQ[1] = *(const bf16x8*)(src + 32);
    }
    __syncthreads();

    // phase 1: S = Q K^T  (wave computes 16 x 256)
    f32x4 sc[16];
    #pragma unroll
    for (int nc = 0; nc < 16; nc++) {
        f32x4 acc = {0.f, 0.f, 0.f, 0.f};
        int row = nc * 16 + l15;
        int s0 = quad ^ (row & 7);
        bf16x8 b0 = *(const bf16x8*)&kvs[row * HD_ + s0 * 8];
        bf16x8 b1 = *(const bf16x8*)&kvs[row * HD_ + (s0 ^ 4) * 8];
        acc = __builtin_amdgcn_mfma_f32_16x16x32_bf16(aQ[0], b0, acc, 0, 0, 0);
        acc = __builtin_amdgcn_mfma_f32_16x16x32_bf16(aQ[1], b1, acc, 0, 0, 0);
        sc[nc] = acc;
    }
    const float scale = 0.125f;  // 1/sqrt(64)
    float rmax[4], rinv[4];
    #pragma unroll
    for (int r = 0; r < 4; r++) {
        float mx = -1e30f;
        #pragma unroll
        for (int nc = 0; nc < 16; nc++) mx = fmaxf(mx, sc[nc][r]);
        for (int off = 1; off < 16; off <<= 1) mx = fmaxf(mx, __shfl_xor(mx, off));
        rmax[r] = mx * scale;
    }
    #pragma unroll
    for (int r = 0; r < 4; r++) {
        float sum = 0.f;
        #pragma unroll
        for (int nc = 0; nc < 16; nc++) {
            float p = __expf(sc[nc][r] * scale - rmax[r]);
            sc[nc][r] = p;
            sum += p;
        }
        for (int off = 1; off < 16; off <<= 1) sum += __shfl_xor(sum, off);
        rinv[r] = 1.0f / sum;
    }
    // P store (bf16), chunk-swizzled per row
    #pragma unroll
    for (int nc = 0; nc < 16; nc++)
        #pragma unroll
        for (int r = 0; r < 4; r++) {
            int prow = quad * 4 + r;
            int col = nc * 16 + l15;
            int slot = (col >> 3) ^ (prow & 7);
            P[w * 4096 + prow * 256 + slot * 8 + (col & 7)] =
                f2bf(sc[nc][r] * rinv[r]);
        }
    __syncthreads();  // all waves done reading K + writing P

    // stage V^T[64 d][256 s], chunk-swizzled: row d, chunk c at slot c^(d&7)
    {
        const u16* src = qkv + (rowb + t) * QKV3 + 2 * D_ + h * HD_;
        int chunkc = t >> 3, bytec = t & 7;
        #pragma unroll
        for (int dj = 0; dj < 8; dj++) {
            uint4 x = *(const uint4*)(src + dj * 8);
            const u16* xs = (const u16*)&x;
            #pragma unroll
            for (int i = 0; i < 8; i++) {
                int vrow = dj * 8 + i;
                kvs[vrow * 256 + ((chunkc ^ (vrow & 7)) * 8) + bytec] = xs[i];
            }
        }
    }
    __syncthreads();

    // phase 2: O = P @ V   (wave: 16 x 64)
    f32x4 accO[4];
    f32x4 zero = {0.f, 0.f, 0.f, 0.f};
    #pragma unroll
    for (int nt = 0; nt < 4; nt++) accO[nt] = zero;
    for (int ks = 0; ks < 8; ks++) {
        int ch = ks * 4 + quad;
        bf16x8 aP = *(const bf16x8*)&P[w * 4096 + l15 * 256 + ((ch ^ (l15 & 7)) * 8)];
        #pragma unroll
        for (int nt = 0; nt < 4; nt++) {
            int vrow = nt * 16 + l15;
            bf16x8 bV = *(const bf16x8*)&kvs[vrow * 256 + ((ch ^ (vrow & 7)) * 8)];
            accO[nt] = __builtin_amdgcn_mfma_f32_16x16x32_bf16(aP, bV, accO[nt], 0, 0, 0);
        }
    }
    #pragma unroll
    for (int nt = 0; nt < 4; nt++)
        #pragma unroll
        for (int r = 0; r < 4; r++) {
            int orow = qc * 64 + w * 16 + quad * 4 + r;
            o[(rowb + orow) * D_ + h * HD_ + nt * 16 + l15] = f2bf(accO[nt][r]);
        }
}

// ---------------------------------------------------------------------------
// LayerNorm: out = LN(in [+ in2] [+ res]) * g + b, optional GELU / PE.
// ---------------------------------------------------------------------------
template <int WIDTH, bool RES, bool GELU, bool PE, bool SUM2>
__global__ __launch_bounds__(WIDTH) void ln_kernel(
    const float* __restrict__ in, const float* __restrict__ in2,
    const u16* __restrict__ res,
    const float* __restrict__ g, const float* __restrict__ b,
    u16* __restrict__ out)
{
    __shared__ float rs[8], rq[8];
    int row = blockIdx.x;
    int t = threadIdx.x;
    size_t base = (size_t)row * WIDTH;
    float v = in[base + t];
    if (SUM2) v += in2[base + t];
    if (RES) v += bf2f(res[base + t]);
    float sm = v, sq = v * v;
    for (int off = 32; off; off >>= 1) {
        sm += __shfl_xor(sm, off);
        sq += __shfl_xor(sq, off);
    }
    constexpr int NW = WIDTH / 64;
    if ((t & 63) == 0) { rs[t >> 6] = sm; rq[t >> 6] = sq; }
    __syncthreads();
    float ts = 0.f, tq = 0.f;
    #pragma unroll
    for (int i = 0; i < NW; i++) { ts += rs[i]; tq += rq[i]; }
    float mean = ts / (float)WIDTH;
    float var = tq / (float)WIDTH - mean * mean;
    float rstd = rsqrtf(var + 1e-5f);
    float y = (v - mean) * rstd * g[t] + b[t];
    if (GELU) y = gelu_f(y);
    if (PE) {
        const float c = -9.210340371976184f / (float)D_;  // -ln(10000)/D
        int s = row & (S_ - 1);
        int i2 = t >> 1;
        float ang = (float)s * __expf((float)(2 * i2) * c);
        y += (t & 1) ? __cosf(ang) : __sinf(ang);
    }
    out[base + t] = f2bf(y);
}

// ---------------------------------------------------------------------------
// Head: out = tanh(y2 @ Wp3 + bp3) * scale + bias. 8 rows x 32 cols per block.
// ---------------------------------------------------------------------------
__global__ __launch_bounds__(256) void head_kernel(
    const u16* __restrict__ y2, const float* __restrict__ W,
    const float* __restrict__ bias, const float* __restrict__ scl,
    const float* __restrict__ bs, float* __restrict__ out)
{
    __shared__ float Ws[128 * ACT_];
    __shared__ u16 Ys[8 * 128];
    int t = threadIdx.x;
    for (int i = t; i < 128 * ACT_; i += 256) Ws[i] = W[i];
    int r0 = blockIdx.x * 8;
    for (int i = t; i < 8 * 128; i += 256) Ys[i] = y2[(size_t)r0 * 128 + i];
    __syncthreads();
    int lr = t >> 5, c = t & 31;
    if (c < ACT_) {
        float acc = bias[c];
        for (int kk = 0; kk < 128; kk++)
            acc += bf2f(Ys[lr * 128 + kk]) * Ws[kk * ACT_ + c];
        float y = tanhf(acc);
        out[(size_t)(r0 + lr) * ACT_ + c] = y * scl[c] + bs[c];
    }
}

// ---------------------------------------------------------------------------
extern "C" void kernel_launch(void* const* d_in, const int* in_sizes, int n_in,
                              void* d_out, int out_size, void* d_ws, size_t ws_size,
                              hipStream_t stream)
{
    const float* obs   = (const float*)d_in[0];
    const float* W_in  = (const float*)d_in[1];
    const float* b_in  = (const float*)d_in[2];
    const float* g_in  = (const float*)d_in[3];
    const float* be_in = (const float*)d_in[4];
    const float* Wq  = (const float*)d_in[5];
    const float* bq  = (const float*)d_in[6];
    const float* Wk  = (const float*)d_in[7];
    const float* bk  = (const float*)d_in[8];
    const float* Wv  = (const float*)d_in[9];
    const float* bv  = (const float*)d_in[10];
    const float* Wo  = (const float*)d_in[11];
    const float* bo  = (const float*)d_in[12];
    const float* g1  = (const float*)d_in[13];
    const float* be1 = (const float*)d_in[14];
    const float* W1  = (const float*)d_in[15];
    const float* b1  = (const float*)d_in[16];
    const float* W2  = (const float*)d_in[17];
    const float* b2  = (const float*)d_in[18];
    const float* g2  = (const float*)d_in[19];
    const float* be2 = (const float*)d_in[20];
    const float* Wp1  = (const float*)d_in[21];
    const float* bp1  = (const float*)d_in[22];
    const float* gp1  = (const float*)d_in[23];
    const float* bep1 = (const float*)d_in[24];
    const float* Wp2  = (const float*)d_in[25];
    const float* bp2  = (const float*)d_in[26];
    const float* gp2  = (const float*)d_in[27];
    const float* bep2 = (const float*)d_in[28];
    const float* Wp3  = (const float*)d_in[29];
    const float* bp3  = (const float*)d_in[30];
    const float* ascl = (const float*)d_in[31];
    const float* abias = (const float*)d_in[32];

    char* ws = (char*)d_ws;
    size_t off = 0;
    auto alloc = [&](size_t bytes) {
        void* p = ws + off;
        off += (bytes + 255) & ~(size_t)255;
        return p;
    };
    u16* WQKVT = (u16*)alloc((size_t)L_ * QKV3 * D_ * 2);     // 12.6 MB
    u16* WOT   = (u16*)alloc((size_t)L_ * D_ * D_ * 2);       // 4 MB
    u16* W1T   = (u16*)alloc((size_t)L_ * D_ * FF_ * 2);      // 16 MB
    u16* W2T   = (u16*)alloc((size_t)L_ * FF_ * D_ * 2);      // 16 MB
    u16* WP1T  = (u16*)alloc((size_t)D_ * (D_ / 2) * 2);
    u16* WP2T  = (u16*)alloc((size_t)(D_ / 2) * (D_ / 4) * 2);
    float* bqkv = (float*)alloc((size_t)L_ * QKV3 * 4);
    u16* x_bf = (u16*)alloc((size_t)NTOK * D_ * 2);           // 16 MB
    float* tmp = (float*)alloc((size_t)NTOK * D_ * 4);        // 32 MB
    char* regionA = (char*)alloc((size_t)NTOK * FF_ * 2);     // 64 MB
    size_t base_need = off;
    float* tmp2 = (float*)(ws + base_need);                   // +16 MB if fits
    bool split = (ws_size >= base_need + (size_t)NTOK * (D_ / 2) * 4);
    (void)in_sizes; (void)n_in; (void)out_size;

    u16* qkvbuf = (u16*)(regionA);                            // 48 MB
    u16* obuf = (u16*)(regionA + (size_t)NTOK * QKV3 * 2);    // 16 MB
    u16* hbuf = (u16*)(regionA);                              // 64 MB (aliases)
    // head-phase aliases (regionA free then)
    float* p1out = tmp;                                       // [NTOK][256] f32
    float* p1part = tmp2;
    u16* y1_bf = (u16*)(regionA);                             // 8 MB
    float* p2out = tmp;                                       // [NTOK][128] f32
    float* p2part = tmp2;
    u16* y2_bf = (u16*)(regionA + (32u << 20));               // 4 MB

    dim3 tb(32, 8);
    size_t DD = (size_t)D_ * D_;
    transpose_bf16_kernel<<<dim3(16, 16, L_), tb, 0, stream>>>(
        Wq, WQKVT, D_, D_, DD, (size_t)QKV3 * D_);
    transpose_bf16_kernel<<<dim3(16, 16, L_), tb, 0, stream>>>(
        Wk, WQKVT + DD, D_, D_, DD, (size_t)QKV3 * D_);
    transpose_bf16_kernel<<<dim3(16, 16, L_), tb, 0, stream>>>(
        Wv, WQKVT + 2 * DD, D_, D_, DD, (size_t)QKV3 * D_);
    transpose_bf16_kernel<<<dim3(16, 16, L_), tb, 0, stream>>>(
        Wo, WOT, D_, D_, DD, DD);
    transpose_bf16_kernel<<<dim3(64, 16, L_), tb, 0, stream>>>(
        W1, W1T, D_, FF_, (size_t)D_ * FF_, (size_t)D_ * FF_);
    transpose_bf16_kernel<<<dim3(16, 64, L_), tb, 0, stream>>>(
        W2, W2T, FF_, D_, (size_t)D_ * FF_, (size_t)D_ * FF_);
    transpose_bf16_kernel<<<dim3(8, 16, 1), tb, 0, stream>>>(
        Wp1, WP1T, D_, D_ / 2, 0, 0);
    transpose_bf16_kernel<<<dim3(4, 8, 1), tb, 0, stream>>>(
        Wp2, WP2T, D_ / 2, D_ / 4, 0, 0);
    concat_bias_kernel<<<L_ * QKV3 / 256, 256, 0, stream>>>(bq, bk, bv, bqkv);

    in_gemm_kernel<<<dim3(D_ / 64, NTOK / 64), 256, 0, stream>>>(
        obs, W_in, b_in, tmp);
    ln_kernel<D_, false, true, true, false><<<NTOK, D_, 0, stream>>>(
        tmp, nullptr, nullptr, g_in, be_in, x_bf);

    const int MG = NTOK / 128;  // 128
    for (int l = 0; l < L_; l++) {
        const u16* wqkvt = WQKVT + (size_t)l * QKV3 * D_;
        const u16* wot = WOT + (size_t)l * DD;
        const u16* w1t = W1T + (size_t)l * D_ * FF_;
        const u16* w2t = W2T + (size_t)l * FF_ * D_;

        gemm_bt_kernel<0, 128, false><<<dim3(QKV3 / 128, MG), 256, 0, stream>>>(
            x_bf, wqkvt, bqkv + l * QKV3, qkvbuf, nullptr, NTOK, QKV3, D_, D_);
        attn_kernel<<<B_ * H_ * (S_ / 64), 256, 0, stream>>>(qkvbuf, obuf);
        gemm_bt_kernel<2, 64, false><<<dim3(D_ / 64, MG), 256, 0, stream>>>(
            obuf, wot, bo + l * D_, tmp, nullptr, NTOK, D_, D_, D_);
        ln_kernel<D_, true, false, false, false><<<NTOK, D_, 0, stream>>>(
            tmp, nullptr, x_bf, g1 + l * D_, be1 + l * D_, x_bf);
        gemm_bt_kernel<1, 128, false><<<dim3(FF_ / 128, MG), 256, 0, stream>>>(
            x_bf, w1t, b1 + l * FF_, hbuf, nullptr, NTOK, FF_, D_, D_);
        gemm_bt_kernel<2, 64, false><<<dim3(D_ / 64, MG), 256, 0, stream>>>(
            hbuf, w2t, b2 + l * D_, tmp, nullptr, NTOK, D_, FF_, FF_);
        ln_kernel<D_, true, false, false, false><<<NTOK, D_, 0, stream>>>(
            tmp, nullptr, x_bf, g2 + l * D_, be2 + l * D_, x_bf);
    }

    // policy head
    if (split) {
        gemm_bt_kernel<2, 64, true><<<dim3(4, MG, 2), 256, 0, stream>>>(
            x_bf, WP1T, bp1, p1out, p1part, NTOK, D_ / 2, D_, D_ / 2);
        ln_kernel<D_ / 2, false, true, false, true><<<NTOK, D_ / 2, 0, stream>>>(
            p1out, p1part, nullptr, gp1, bep1, y1_bf);
        gemm_bt_kernel<2, 64, true><<<dim3(2, MG, 2), 256, 0, stream>>>(
            y1_bf, WP2T, bp2, p2out, p2part, NTOK, D_ / 4, D_ / 2, D_ / 4);
        ln_kernel<D_ / 4, false, true, false, true><<<NTOK, D_ / 4, 0, stream>>>(
            p2out, p2part, nullptr, gp2, bep2, y2_bf);
    } else {
        gemm_bt_kernel<2, 64, false><<<dim3(4, MG), 256, 0, stream>>>(
            x_bf, WP1T, bp1, p1out, nullptr, NTOK, D_ / 2, D_, D_);
        ln_kernel<D_ / 2, false, true, false, false><<<NTOK, D_ / 2, 0, stream>>>(
            p1out, nullptr, nullptr, gp1, bep1, y1_bf);
        gemm_bt_kernel<2, 64, false><<<dim3(2, MG), 256, 0, stream>>>(
            y1_bf, WP2T, bp2, p2out, nullptr, NTOK, D_ / 4, D_ / 2, D_ / 2);
        ln_kernel<D_ / 4, false, true, false, false><<<NTOK, D_ / 4, 0, stream>>>(
            p2out, nullptr, nullptr, gp2, bep2, y2_bf);
    }
    head_kernel<<<NTOK / 8, 256, 0, stream>>>(
        y2_bf, Wp3, bp3, ascl, abias, (float*)d_out);
}

// Round 6
// 2552.798 us; speedup vs baseline: 1.0654x; 1.0637x over previous
//
#include <hip/hip_runtime.h>

typedef unsigned short u16;
typedef unsigned int u32;
typedef __attribute__((ext_vector_type(8))) __bf16 bf16x8;
typedef __attribute__((ext_vector_type(4))) float f32x4;

#define B_ 64
#define S_ 256
#define OBS_ 96
#define ACT_ 29
#define D_ 512
#define H_ 8
#define L_ 8
#define FF_ 2048
#define HD_ 64
#define NTOK (B_ * S_)   // 16384
#define QKV3 (3 * D_)    // 1536

__device__ __forceinline__ u16 f2bf(float f) {
    u32 u = __float_as_uint(f);
    u += 0x7FFFu + ((u >> 16) & 1u);
    return (u16)(u >> 16);
}
__device__ __forceinline__ float bf2f(u16 h) {
    return __uint_as_float(((u32)h) << 16);
}
// 7-inst GELU: x*sigmoid(2z), z = 0.79788456(x+0.044715x^3), exp2/rcp form.
__device__ __forceinline__ float gelu_f(float x) {
    const float k1 = 2.3022121f;    // 2*0.79788456*log2(e)
    const float k2 = 0.10294451f;   // k1*0.044715
    float x2 = x * x;
    float arg = x * __builtin_fmaf(x2, k2, k1);
    float e = exp2f(arg);
    float r = __builtin_amdgcn_rcpf(1.0f + e);
    return __builtin_fmaf(-x, r, x);
}
// async global->LDS, 16B per lane. LDS dest is wave-uniform base + lane*16.
__device__ __forceinline__ void gld_lds16(const u16* g, u16* l) {
    __builtin_amdgcn_global_load_lds(
        (const __attribute__((address_space(1))) unsigned int*)g,
        (__attribute__((address_space(3))) unsigned int*)l, 16, 0, 0);
}

// ---------------------------------------------------------------------------
// Transpose + downcast: src fp32 [z][K][N] -> dst bf16 [z][N][K] (strided)
// ---------------------------------------------------------------------------
__global__ __launch_bounds__(256) void transpose_bf16_kernel(
    const float* __restrict__ src, u16* __restrict__ dst, int K, int N,
    size_t srcStride, size_t dstStride)
{
    __shared__ float tile[32][33];
    int n0 = blockIdx.x * 32, k0 = blockIdx.y * 32;
    const float* s = src + (size_t)blockIdx.z * srcStride;
    u16* d = dst + (size_t)blockIdx.z * dstStride;
    int tx = threadIdx.x, ty = threadIdx.y;   // block (32,8)
    for (int i = 0; i < 32; i += 8)
        tile[ty + i][tx] = s[(size_t)(k0 + ty + i) * N + n0 + tx];
    __syncthreads();
    for (int i = 0; i < 32; i += 8)
        d[(size_t)(n0 + ty + i) * K + k0 + tx] = f2bf(tile[tx][ty + i]);
}

__global__ __launch_bounds__(256) void concat_bias_kernel(
    const float* __restrict__ bq, const float* __restrict__ bk,
    const float* __restrict__ bv, float* __restrict__ dst)
{
    int i = blockIdx.x * 256 + threadIdx.x;      // over L*1536
    int l = i / QKV3, r = i - l * QKV3;
    float v;
    if (r < D_)            v = bq[l * D_ + r];
    else if (r < 2 * D_)   v = bk[l * D_ + r - D_];
    else                   v = bv[l * D_ + r - 2 * D_];
    dst[i] = v;
}

// ---------------------------------------------------------------------------
// Input projection GEMM (fp32): outp[M][512] = obs[M][96] @ Win[96][512] + b
// ---------------------------------------------------------------------------
__global__ __launch_bounds__(256) void in_gemm_kernel(
    const float* __restrict__ obs, const float* __restrict__ Win,
    const float* __restrict__ b_in, float* __restrict__ outp)
{
    __shared__ float As[OBS_][68];
    __shared__ float Bs[OBS_][68];
    int m0 = blockIdx.y * 64, n0 = blockIdx.x * 64;
    int t = threadIdx.x;
    #pragma unroll
    for (int i = 0; i < 24; i++) {
        int idx = i * 256 + t;
        int m = idx / OBS_, kk = idx - m * OBS_;
        As[kk][m] = obs[(size_t)(m0 + m) * OBS_ + kk];
    }
    #pragma unroll
    for (int i = 0; i < 24; i++) {
        int idx = i * 256 + t;
        int kk = idx >> 6, n = idx & 63;
        Bs[kk][n] = Win[(size_t)kk * D_ + n0 + n];
    }
    __syncthreads();
    int tm = t >> 4, tn = t & 15;
    float acc[4][4] = {};
    for (int kk = 0; kk < OBS_; kk++) {
        float4 a = *(const float4*)&As[kk][tm * 4];
        float4 b = *(const float4*)&Bs[kk][tn * 4];
        const float av[4] = {a.x, a.y, a.z, a.w};
        const float bv[4] = {b.x, b.y, b.z, b.w};
        #pragma unroll
        for (int r = 0; r < 4; r++)
            #pragma unroll
            for (int c = 0; c < 4; c++) acc[r][c] += av[r] * bv[c];
    }
    #pragma unroll
    for (int r = 0; r < 4; r++)
        #pragma unroll
        for (int c = 0; c < 4; c++) {
            int col = n0 + tn * 4 + c;
            outp[(size_t)(m0 + tm * 4 + r) * D_ + col] = acc[r][c] + b_in[col];
        }
}

// ---------------------------------------------------------------------------
// GEMM: C[M][N] = A[M][K] @ BT[N][K] + bias (bf16 in, LDS chunk-swizzled)
// BK=64 (two 32-wide MFMA sub-steps per barrier). Y-fast 1D grid:
//   y = bx & 127 (M always 16384), x = bx >> 7  -> same-row blocks co-XCD.
// EPI: 0 = bf16 out, 1 = bf16+GELU, 2 = fp32 out
// TN: 128 or 64. SPLITK: gridDim.z==2; z=0 -> C(+bias), z=1 -> C2 (no bias).
// ---------------------------------------------------------------------------
template <int EPI, int TN, bool SPLITK>
__global__ __launch_bounds__(256) void gemm_bt_kernel(
    const u16* __restrict__ A, const u16* __restrict__ BT,
    const float* __restrict__ bias, void* __restrict__ C,
    float* __restrict__ C2, int M, int N, int K, int kLen)
{
    constexpr int NI = TN / 32;               // acc tiles per wave in N
    constexpr int NB = TN / 32;               // B staging chunks per thread
    __shared__ __align__(16) u16 As[128 * 64];
    __shared__ __align__(16) u16 Bs[TN * 64];
    int bx = blockIdx.x;
    int m0 = (bx & 127) * 128, n0 = (bx >> 7) * TN;
    int z = SPLITK ? blockIdx.z : 0;
    int kStart = z * kLen;
    int t = threadIdx.x;
    int lane = t & 63, w = t >> 6;
    int wm = w >> 1, wn = w & 1;
    int l15 = lane & 15, quad = lane >> 4;

    // staging: rows of 8 chunks (16B each); LDS slot s in row r holds global
    // chunk s^(r&7). Lane-contiguous LDS dest (global_load_lds constraint).
    const u16* gA[4]; u16* lA[4];
    #pragma unroll
    for (int i = 0; i < 4; i++) {
        int ci = t + i * 256;                 // 1024 chunks of A
        int r = ci >> 3, s = ci & 7, gc = s ^ (r & 7);
        gA[i] = A + (size_t)(m0 + r) * K + kStart + gc * 8;
        lA[i] = &As[ci * 8];
    }
    const u16* gB[NB]; u16* lB[NB];
    #pragma unroll
    for (int i = 0; i < NB; i++) {
        int ci = t + i * 256;                 // TN*8 chunks of B
        int r = ci >> 3, s = ci & 7, gc = s ^ (r & 7);
        gB[i] = BT + (size_t)(n0 + r) * K + kStart + gc * 8;
        lB[i] = &Bs[ci * 8];
    }

    // fragment offsets (elements), per k-half
    int aoff[2][4], boff[2][NI];
    #pragma unroll
    for (int kh = 0; kh < 2; kh++) {
        #pragma unroll
        for (int mi = 0; mi < 4; mi++) {
            int row = wm * 64 + mi * 16 + l15;
            aoff[kh][mi] = row * 64 + (((kh * 4 + quad) ^ (row & 7)) * 8);
        }
        #pragma unroll
        for (int ni = 0; ni < NI; ni++) {
            int row = wn * (TN / 2) + ni * 16 + l15;
            boff[kh][ni] = row * 64 + (((kh * 4 + quad) ^ (row & 7)) * 8);
        }
    }

    f32x4 acc[4][NI];
    f32x4 zero = {0.f, 0.f, 0.f, 0.f};
    #pragma unroll
    for (int mi = 0; mi < 4; mi++)
        #pragma unroll
        for (int ni = 0; ni < NI; ni++) acc[mi][ni] = zero;

    for (int kk = 0; kk < kLen; kk += 64) {
        __syncthreads();
        #pragma unroll
        for (int i = 0; i < 4; i++) { gld_lds16(gA[i], lA[i]); gA[i] += 64; }
        #pragma unroll
        for (int i = 0; i < NB; i++) { gld_lds16(gB[i], lB[i]); gB[i] += 64; }
        __syncthreads();
        #pragma unroll
        for (int kh = 0; kh < 2; kh++) {
            bf16x8 a[4], b[NI];
            #pragma unroll
            for (int mi = 0; mi < 4; mi++)
                a[mi] = *(const bf16x8*)&As[aoff[kh][mi]];
            #pragma unroll
            for (int ni = 0; ni < NI; ni++)
                b[ni] = *(const bf16x8*)&Bs[boff[kh][ni]];
            #pragma unroll
            for (int mi = 0; mi < 4; mi++)
                #pragma unroll
                for (int ni = 0; ni < NI; ni++)
                    acc[mi][ni] = __builtin_amdgcn_mfma_f32_16x16x32_bf16(
                        a[mi], b[ni], acc[mi][ni], 0, 0, 0);
        }
    }

    bool partial = SPLITK && (z == 1);
    #pragma unroll
    for (int ni = 0; ni < NI; ni++) {
        int col = n0 + wn * (TN / 2) + ni * 16 + l15;
        float bv = partial ? 0.f : bias[col];
        #pragma unroll
        for (int mi = 0; mi < 4; mi++) {
            int rbase = m0 + wm * 64 + mi * 16 + quad * 4;
            f32x4 v = acc[mi][ni];
            #pragma unroll
            for (int r = 0; r < 4; r++) {
                float y = v[r] + bv;
                size_t idx = (size_t)(rbase + r) * N + col;
                if (partial)         C2[idx] = y;
                else if (EPI == 2)   ((float*)C)[idx] = y;
                else if (EPI == 1)   ((u16*)C)[idx] = f2bf(gelu_f(y));
                else                 ((u16*)C)[idx] = f2bf(y);
            }
        }
    }
}

// ---------------------------------------------------------------------------
// Attention on fused qkv [NTOK][1536]. Block = (b,h,64 q rows). LDS swizzled.
// ---------------------------------------------------------------------------
__global__ __launch_bounds__(256) void attn_kernel(
    const u16* __restrict__ qkv, u16* __restrict__ o)
{
    __shared__ __align__(16) u16 kvs[S_ * HD_];      // 32 KB: K rows, then V^T
    __shared__ __align__(16) u16 P[4 * 16 * S_];     // 32 KB: per-wave probs
    int bx = blockIdx.x;
    int qc = bx & 3;
    int h = (bx >> 2) & 7;
    int b = bx >> 5;
    int t = threadIdx.x;
    int lane = t & 63, w = t >> 6;
    int l15 = lane & 15, quad = lane >> 4;
    size_t rowb = (size_t)b * S_;

    // stage K rows, chunk-swizzled: row t, chunk j at slot j^(t&7)
    {
        const u16* src = qkv + (rowb + t) * QKV3 + D_ + h * HD_;
        int sw = t & 7;
        #pragma unroll
        for (int j = 0; j < 8; j++)
            *(uint4*)&kvs[t * HD_ + ((j ^ sw) * 8)] = *(const uint4*)(src + j * 8);
    }
    bf16x8 aQ[2];
    {
        int qrow = qc * 64 + w * 16 + l15;
        const u16* src = qkv + (rowb + qrow) * QKV3 + h * HD_ + quad * 8;
        aQ[0] = *(const bf16x8*)(src);
        aQ[1] = *(const bf16x8*)(src + 32);
    }
    __syncthreads();

    // phase 1: S = Q K^T  (wave computes 16 x 256)
    f32x4 sc[16];
    #pragma unroll
    for (int nc = 0; nc < 16; nc++) {
        f32x4 acc = {0.f, 0.f, 0.f, 0.f};
        int row = nc * 16 + l15;
        int s0 = quad ^ (row & 7);
        bf16x8 b0 = *(const bf16x8*)&kvs[row * HD_ + s0 * 8];
        bf16x8 b1 = *(const bf16x8*)&kvs[row * HD_ + (s0 ^ 4) * 8];
        acc = __builtin_amdgcn_mfma_f32_16x16x32_bf16(aQ[0], b0, acc, 0, 0, 0);
        acc = __builtin_amdgcn_mfma_f32_16x16x32_bf16(aQ[1], b1, acc, 0, 0, 0);
        sc[nc] = acc;
    }
    const float scale = 0.125f;  // 1/sqrt(64)
    float rmax[4], rinv[4];
    #pragma unroll
    for (int r = 0; r < 4; r++) {
        float mx = -1e30f;
        #pragma unroll
        for (int nc = 0; nc < 16; nc++) mx = fmaxf(mx, sc[nc][r]);
        for (int off = 1; off < 16; off <<= 1) mx = fmaxf(mx, __shfl_xor(mx, off));
        rmax[r] = mx * scale;
    }
    #pragma unroll
    for (int r = 0; r < 4; r++) {
        float sum = 0.f;
        #pragma unroll
        for (int nc = 0; nc < 16; nc++) {
            float p = __expf(sc[nc][r] * scale - rmax[r]);
            sc[nc][r] = p;
            sum += p;
        }
        for (int off = 1; off < 16; off <<= 1) sum += __shfl_xor(sum, off);
        rinv[r] = 1.0f / sum;
    }
    // P store (bf16), chunk-swizzled per row
    #pragma unroll
    for (int nc = 0; nc < 16; nc++)
        #pragma unroll
        for (int r = 0; r < 4; r++) {
            int prow = quad * 4 + r;
            int col = nc * 16 + l15;
            int slot = (col >> 3) ^ (prow & 7);
            P[w * 4096 + prow * 256 + slot * 8 + (col & 7)] =
                f2bf(sc[nc][r] * rinv[r]);
        }
    __syncthreads();  // all waves done reading K + writing P

    // stage V^T[64 d][256 s], chunk-swizzled: row d, chunk c at slot c^(d&7)
    {
        const u16* src = qkv + (rowb + t) * QKV3 + 2 * D_ + h * HD_;
        int chunkc = t >> 3, bytec = t & 7;
        #pragma unroll
        for (int dj = 0; dj < 8; dj++) {
            uint4 x = *(const uint4*)(src + dj * 8);
            const u16* xs = (const u16*)&x;
            #pragma unroll
            for (int i = 0; i < 8; i++) {
                int vrow = dj * 8 + i;
                kvs[vrow * 256 + ((chunkc ^ (vrow & 7)) * 8) + bytec] = xs[i];
            }
        }
    }
    __syncthreads();

    // phase 2: O = P @ V   (wave: 16 x 64)
    f32x4 accO[4];
    f32x4 zero = {0.f, 0.f, 0.f, 0.f};
    #pragma unroll
    for (int nt = 0; nt < 4; nt++) accO[nt] = zero;
    for (int ks = 0; ks < 8; ks++) {
        int ch = ks * 4 + quad;
        bf16x8 aP = *(const bf16x8*)&P[w * 4096 + l15 * 256 + ((ch ^ (l15 & 7)) * 8)];
        #pragma unroll
        for (int nt = 0; nt < 4; nt++) {
            int vrow = nt * 16 + l15;
            bf16x8 bV = *(const bf16x8*)&kvs[vrow * 256 + ((ch ^ (vrow & 7)) * 8)];
            accO[nt] = __builtin_amdgcn_mfma_f32_16x16x32_bf16(aP, bV, accO[nt], 0, 0, 0);
        }
    }
    #pragma unroll
    for (int nt = 0; nt < 4; nt++)
        #pragma unroll
        for (int r = 0; r < 4; r++) {
            int orow = qc * 64 + w * 16 + quad * 4 + r;
            o[(rowb + orow) * D_ + h * HD_ + nt * 16 + l15] = f2bf(accO[nt][r]);
        }
}

// ---------------------------------------------------------------------------
// LayerNorm: out = LN(in [+ in2] [+ res]) * g + b, optional GELU / PE.
// ---------------------------------------------------------------------------
template <int WIDTH, bool RES, bool GELU, bool PE, bool SUM2>
__global__ __launch_bounds__(WIDTH) void ln_kernel(
    const float* __restrict__ in, const float* __restrict__ in2,
    const u16* __restrict__ res,
    const float* __restrict__ g, const float* __restrict__ b,
    u16* __restrict__ out)
{
    __shared__ float rs[8], rq[8];
    int row = blockIdx.x;
    int t = threadIdx.x;
    size_t base = (size_t)row * WIDTH;
    float v = in[base + t];
    if (SUM2) v += in2[base + t];
    if (RES) v += bf2f(res[base + t]);
    float sm = v, sq = v * v;
    for (int off = 32; off; off >>= 1) {
        sm += __shfl_xor(sm, off);
        sq += __shfl_xor(sq, off);
    }
    constexpr int NW = WIDTH / 64;
    if ((t & 63) == 0) { rs[t >> 6] = sm; rq[t >> 6] = sq; }
    __syncthreads();
    float ts = 0.f, tq = 0.f;
    #pragma unroll
    for (int i = 0; i < NW; i++) { ts += rs[i]; tq += rq[i]; }
    float mean = ts / (float)WIDTH;
    float var = tq / (float)WIDTH - mean * mean;
    float rstd = rsqrtf(var + 1e-5f);
    float y = (v - mean) * rstd * g[t] + b[t];
    if (GELU) y = gelu_f(y);
    if (PE) {
        const float c = -9.210340371976184f / (float)D_;  // -ln(10000)/D
        int s = row & (S_ - 1);
        int i2 = t >> 1;
        float ang = (float)s * __expf((float)(2 * i2) * c);
        y += (t & 1) ? __cosf(ang) : __sinf(ang);
    }
    out[base + t] = f2bf(y);
}

// ---------------------------------------------------------------------------
// Head: out = tanh(y2 @ Wp3 + bp3) * scale + bias. 8 rows x 32 cols per block.
// ---------------------------------------------------------------------------
__global__ __launch_bounds__(256) void head_kernel(
    const u16* __restrict__ y2, const float* __restrict__ W,
    const float* __restrict__ bias, const float* __restrict__ scl,
    const float* __restrict__ bs, float* __restrict__ out)
{
    __shared__ float Ws[128 * ACT_];
    __shared__ u16 Ys[8 * 128];
    int t = threadIdx.x;
    for (int i = t; i < 128 * ACT_; i += 256) Ws[i] = W[i];
    int r0 = blockIdx.x * 8;
    for (int i = t; i < 8 * 128; i += 256) Ys[i] = y2[(size_t)r0 * 128 + i];
    __syncthreads();
    int lr = t >> 5, c = t & 31;
    if (c < ACT_) {
        float acc = bias[c];
        for (int kk = 0; kk < 128; kk++)
            acc += bf2f(Ys[lr * 128 + kk]) * Ws[kk * ACT_ + c];
        float y = tanhf(acc);
        out[(size_t)(r0 + lr) * ACT_ + c] = y * scl[c] + bs[c];
    }
}

// ---------------------------------------------------------------------------
extern "C" void kernel_launch(void* const* d_in, const int* in_sizes, int n_in,
                              void* d_out, int out_size, void* d_ws, size_t ws_size,
                              hipStream_t stream)
{
    const float* obs   = (const float*)d_in[0];
    const float* W_in  = (const float*)d_in[1];
    const float* b_in  = (const float*)d_in[2];
    const float* g_in  = (const float*)d_in[3];
    const float* be_in = (const float*)d_in[4];
    const float* Wq  = (const float*)d_in[5];
    const float* bq  = (const float*)d_in[6];
    const float* Wk  = (const float*)d_in[7];
    const float* bk  = (const float*)d_in[8];
    const float* Wv  = (const float*)d_in[9];
    const float* bv  = (const float*)d_in[10];
    const float* Wo  = (const float*)d_in[11];
    const float* bo  = (const float*)d_in[12];
    const float* g1  = (const float*)d_in[13];
    const float* be1 = (const float*)d_in[14];
    const float* W1  = (const float*)d_in[15];
    const float* b1  = (const float*)d_in[16];
    const float* W2  = (const float*)d_in[17];
    const float* b2  = (const float*)d_in[18];
    const float* g2  = (const float*)d_in[19];
    const float* be2 = (const float*)d_in[20];
    const float* Wp1  = (const float*)d_in[21];
    const float* bp1  = (const float*)d_in[22];
    const float* gp1  = (const float*)d_in[23];
    const float* bep1 = (const float*)d_in[24];
    const float* Wp2  = (const float*)d_in[25];
    const float* bp2  = (const float*)d_in[26];
    const float* gp2  = (const float*)d_in[27];
    const float* bep2 = (const float*)d_in[28];
    const float* Wp3  = (const float*)d_in[29];
    const float* bp3  = (const float*)d_in[30];
    const float* ascl = (const float*)d_in[31];
    const float* abias = (const float*)d_in[32];

    char* ws = (char*)d_ws;
    size_t off = 0;
    auto alloc = [&](size_t bytes) {
        void* p = ws + off;
        off += (bytes + 255) & ~(size_t)255;
        return p;
    };
    u16* WQKVT = (u16*)alloc((size_t)L_ * QKV3 * D_ * 2);     // 12.6 MB
    u16* WOT   = (u16*)alloc((size_t)L_ * D_ * D_ * 2);       // 4 MB
    u16* W1T   = (u16*)alloc((size_t)L_ * D_ * FF_ * 2);      // 16 MB
    u16* W2T   = (u16*)alloc((size_t)L_ * FF_ * D_ * 2);      // 16 MB
    u16* WP1T  = (u16*)alloc((size_t)D_ * (D_ / 2) * 2);
    u16* WP2T  = (u16*)alloc((size_t)(D_ / 2) * (D_ / 4) * 2);
    float* bqkv = (float*)alloc((size_t)L_ * QKV3 * 4);
    u16* x_bf = (u16*)alloc((size_t)NTOK * D_ * 2);           // 16 MB
    float* tmp = (float*)alloc((size_t)NTOK * D_ * 4);        // 32 MB
    char* regionA = (char*)alloc((size_t)NTOK * FF_ * 2);     // 64 MB
    size_t base_need = off;
    float* tmp2 = (float*)(ws + base_need);                   // +32 MB if fits
    bool split = (ws_size >= base_need + (size_t)NTOK * D_ * 4);
    (void)in_sizes; (void)n_in; (void)out_size;

    u16* qkvbuf = (u16*)(regionA);                            // 48 MB
    u16* obuf = (u16*)(regionA + (size_t)NTOK * QKV3 * 2);    // 16 MB
    u16* hbuf = (u16*)(regionA);                              // 64 MB (aliases)
    // head-phase aliases (regionA free then)
    float* p1out = tmp;                                       // [NTOK][256] f32
    float* p1part = tmp2;
    u16* y1_bf = (u16*)(regionA);                             // 8 MB
    float* p2out = tmp;                                       // [NTOK][128] f32
    float* p2part = tmp2;
    u16* y2_bf = (u16*)(regionA + (32u << 20));               // 4 MB

    dim3 tb(32, 8);
    size_t DD = (size_t)D_ * D_;
    transpose_bf16_kernel<<<dim3(16, 16, L_), tb, 0, stream>>>(
        Wq, WQKVT, D_, D_, DD, (size_t)QKV3 * D_);
    transpose_bf16_kernel<<<dim3(16, 16, L_), tb, 0, stream>>>(
        Wk, WQKVT + DD, D_, D_, DD, (size_t)QKV3 * D_);
    transpose_bf16_kernel<<<dim3(16, 16, L_), tb, 0, stream>>>(
        Wv, WQKVT + 2 * DD, D_, D_, DD, (size_t)QKV3 * D_);
    transpose_bf16_kernel<<<dim3(16, 16, L_), tb, 0, stream>>>(
        Wo, WOT, D_, D_, DD, DD);
    transpose_bf16_kernel<<<dim3(64, 16, L_), tb, 0, stream>>>(
        W1, W1T, D_, FF_, (size_t)D_ * FF_, (size_t)D_ * FF_);
    transpose_bf16_kernel<<<dim3(16, 64, L_), tb, 0, stream>>>(
        W2, W2T, FF_, D_, (size_t)D_ * FF_, (size_t)D_ * FF_);
    transpose_bf16_kernel<<<dim3(8, 16, 1), tb, 0, stream>>>(
        Wp1, WP1T, D_, D_ / 2, 0, 0);
    transpose_bf16_kernel<<<dim3(4, 8, 1), tb, 0, stream>>>(
        Wp2, WP2T, D_ / 2, D_ / 4, 0, 0);
    concat_bias_kernel<<<L_ * QKV3 / 256, 256, 0, stream>>>(bq, bk, bv, bqkv);

    in_gemm_kernel<<<dim3(D_ / 64, NTOK / 64), 256, 0, stream>>>(
        obs, W_in, b_in, tmp);
    ln_kernel<D_, false, true, true, false><<<NTOK, D_, 0, stream>>>(
        tmp, nullptr, nullptr, g_in, be_in, x_bf);

    const int MG = NTOK / 128;  // 128 M-blocks; grid = 128 * NX (y-fast)
    for (int l = 0; l < L_; l++) {
        const u16* wqkvt = WQKVT + (size_t)l * QKV3 * D_;
        const u16* wot = WOT + (size_t)l * DD;
        const u16* w1t = W1T + (size_t)l * D_ * FF_;
        const u16* w2t = W2T + (size_t)l * FF_ * D_;

        gemm_bt_kernel<0, 128, false><<<MG * (QKV3 / 128), 256, 0, stream>>>(
            x_bf, wqkvt, bqkv + l * QKV3, qkvbuf, nullptr, NTOK, QKV3, D_, D_);
        attn_kernel<<<B_ * H_ * (S_ / 64), 256, 0, stream>>>(qkvbuf, obuf);
        if (split) {
            gemm_bt_kernel<2, 128, true><<<dim3(MG * 4, 1, 2), 256, 0, stream>>>(
                obuf, wot, bo + l * D_, tmp, tmp2, NTOK, D_, D_, D_ / 2);
            ln_kernel<D_, true, false, false, true><<<NTOK, D_, 0, stream>>>(
                tmp, tmp2, x_bf, g1 + l * D_, be1 + l * D_, x_bf);
        } else {
            gemm_bt_kernel<2, 128, false><<<MG * 4, 256, 0, stream>>>(
                obuf, wot, bo + l * D_, tmp, nullptr, NTOK, D_, D_, D_);
            ln_kernel<D_, true, false, false, false><<<NTOK, D_, 0, stream>>>(
                tmp, nullptr, x_bf, g1 + l * D_, be1 + l * D_, x_bf);
        }
        gemm_bt_kernel<1, 128, false><<<MG * (FF_ / 128), 256, 0, stream>>>(
            x_bf, w1t, b1 + l * FF_, hbuf, nullptr, NTOK, FF_, D_, D_);
        if (split) {
            gemm_bt_kernel<2, 128, true><<<dim3(MG * 4, 1, 2), 256, 0, stream>>>(
                hbuf, w2t, b2 + l * D_, tmp, tmp2, NTOK, D_, FF_, FF_ / 2);
            ln_kernel<D_, true, false, false, true><<<NTOK, D_, 0, stream>>>(
                tmp, tmp2, x_bf, g2 + l * D_, be2 + l * D_, x_bf);
        } else {
            gemm_bt_kernel<2, 128, false><<<MG * 4, 256, 0, stream>>>(
                hbuf, w2t, b2 + l * D_, tmp, nullptr, NTOK, D_, FF_, FF_);
            ln_kernel<D_, true, false, false, false><<<NTOK, D_, 0, stream>>>(
                tmp, nullptr, x_bf, g2 + l * D_, be2 + l * D_, x_bf);
        }
    }

    // policy head
    if (split) {
        gemm_bt_kernel<2, 64, true><<<dim3(MG * 4, 1, 2), 256, 0, stream>>>(
            x_bf, WP1T, bp1, p1out, p1part, NTOK, D_ / 2, D_, D_ / 2);
        ln_kernel<D_ / 2, false, true, false, true><<<NTOK, D_ / 2, 0, stream>>>(
            p1out, p1part, nullptr, gp1, bep1, y1_bf);
        gemm_bt_kernel<2, 64, true><<<dim3(MG * 2, 1, 2), 256, 0, stream>>>(
            y1_bf, WP2T, bp2, p2out, p2part, NTOK, D_ / 4, D_ / 2, D_ / 4);
        ln_kernel<D_ / 4, false, true, false, true><<<NTOK, D_ / 4, 0, stream>>>(
            p2out, p2part, nullptr, gp2, bep2, y2_bf);
    } else {
        gemm_bt_kernel<2, 64, false><<<MG * 4, 256, 0, stream>>>(
            x_bf, WP1T, bp1, p1out, nullptr, NTOK, D_ / 2, D_, D_);
        ln_kernel<D_ / 2, false, true, false, false><<<NTOK, D_ / 2, 0, stream>>>(
            p1out, nullptr, nullptr, gp1, bep1, y1_bf);
        gemm_bt_kernel<2, 64, false><<<MG * 2, 256, 0, stream>>>(
            y1_bf, WP2T, bp2, p2out, nullptr, NTOK, D_ / 4, D_ / 2, D_ / 2);
        ln_kernel<D_ / 4, false, true, false, false><<<NTOK, D_ / 4, 0, stream>>>(
            p2out, nullptr, nullptr, gp2, bep2, y2_bf);
    }
    head_kernel<<<NTOK / 8, 256, 0, stream>>>(
        y2_bf, Wp3, bp3, ascl, abias, (float*)d_out);
}

// Round 7
// 2376.321 us; speedup vs baseline: 1.1445x; 1.0743x over previous
//
#include <hip/hip_runtime.h>

typedef unsigned short u16;
typedef unsigned int u32;
typedef __attribute__((ext_vector_type(8))) __bf16 bf16x8;
typedef __attribute__((ext_vector_type(4))) float f32x4;

#define B_ 64
#define S_ 256
#define OBS_ 96
#define ACT_ 29
#define D_ 512
#define H_ 8
#define L_ 8
#define FF_ 2048
#define HD_ 64
#define NTOK (B_ * S_)   // 16384
#define QKV3 (3 * D_)    // 1536

__device__ __forceinline__ u16 f2bf(float f) {
    u32 u = __float_as_uint(f);
    u += 0x7FFFu + ((u >> 16) & 1u);
    return (u16)(u >> 16);
}
__device__ __forceinline__ float bf2f(u16 h) {
    return __uint_as_float(((u32)h) << 16);
}
__device__ __forceinline__ u16 f2h(float f) {
    _Float16 h = (_Float16)f;
    u16 u; __builtin_memcpy(&u, &h, 2); return u;
}
__device__ __forceinline__ float h2f(u16 u) {
    _Float16 h; __builtin_memcpy(&h, &u, 2); return (float)h;
}
// 7-inst GELU: x*sigmoid(2z), z = 0.79788456(x+0.044715x^3), exp2/rcp form.
__device__ __forceinline__ float gelu_f(float x) {
    const float k1 = 2.3022121f;    // 2*0.79788456*log2(e)
    const float k2 = 0.10294451f;   // k1*0.044715
    float x2 = x * x;
    float arg = x * __builtin_fmaf(x2, k2, k1);
    float e = exp2f(arg);
    float r = __builtin_amdgcn_rcpf(1.0f + e);
    return __builtin_fmaf(-x, r, x);
}
// async global->LDS, 16B per lane. LDS dest is wave-uniform base + lane*16.
__device__ __forceinline__ void gld_lds16(const u16* g, u16* l) {
    __builtin_amdgcn_global_load_lds(
        (const __attribute__((address_space(1))) unsigned int*)g,
        (__attribute__((address_space(3))) unsigned int*)l, 16, 0, 0);
}

// ---------------------------------------------------------------------------
// Transpose + downcast: src fp32 [z][K][N] -> dst bf16 [z][N][K] (strided)
// ---------------------------------------------------------------------------
__global__ __launch_bounds__(256) void transpose_bf16_kernel(
    const float* __restrict__ src, u16* __restrict__ dst, int K, int N,
    size_t srcStride, size_t dstStride)
{
    __shared__ float tile[32][33];
    int n0 = blockIdx.x * 32, k0 = blockIdx.y * 32;
    const float* s = src + (size_t)blockIdx.z * srcStride;
    u16* d = dst + (size_t)blockIdx.z * dstStride;
    int tx = threadIdx.x, ty = threadIdx.y;   // block (32,8)
    for (int i = 0; i < 32; i += 8)
        tile[ty + i][tx] = s[(size_t)(k0 + ty + i) * N + n0 + tx];
    __syncthreads();
    for (int i = 0; i < 32; i += 8)
        d[(size_t)(n0 + ty + i) * K + k0 + tx] = f2bf(tile[tx][ty + i]);
}

__global__ __launch_bounds__(256) void concat_bias_kernel(
    const float* __restrict__ bq, const float* __restrict__ bk,
    const float* __restrict__ bv, float* __restrict__ dst)
{
    int i = blockIdx.x * 256 + threadIdx.x;      // over L*1536
    int l = i / QKV3, r = i - l * QKV3;
    float v;
    if (r < D_)            v = bq[l * D_ + r];
    else if (r < 2 * D_)   v = bk[l * D_ + r - D_];
    else                   v = bv[l * D_ + r - 2 * D_];
    dst[i] = v;
}

// ---------------------------------------------------------------------------
// Input projection GEMM (fp32): outp[M][512] = obs[M][96] @ Win[96][512] + b
// ---------------------------------------------------------------------------
__global__ __launch_bounds__(256) void in_gemm_kernel(
    const float* __restrict__ obs, const float* __restrict__ Win,
    const float* __restrict__ b_in, float* __restrict__ outp)
{
    __shared__ float As[OBS_][68];
    __shared__ float Bs[OBS_][68];
    int m0 = blockIdx.y * 64, n0 = blockIdx.x * 64;
    int t = threadIdx.x;
    #pragma unroll
    for (int i = 0; i < 24; i++) {
        int idx = i * 256 + t;
        int m = idx / OBS_, kk = idx - m * OBS_;
        As[kk][m] = obs[(size_t)(m0 + m) * OBS_ + kk];
    }
    #pragma unroll
    for (int i = 0; i < 24; i++) {
        int idx = i * 256 + t;
        int kk = idx >> 6, n = idx & 63;
        Bs[kk][n] = Win[(size_t)kk * D_ + n0 + n];
    }
    __syncthreads();
    int tm = t >> 4, tn = t & 15;
    float acc[4][4] = {};
    for (int kk = 0; kk < OBS_; kk++) {
        float4 a = *(const float4*)&As[kk][tm * 4];
        float4 b = *(const float4*)&Bs[kk][tn * 4];
        const float av[4] = {a.x, a.y, a.z, a.w};
        const float bv[4] = {b.x, b.y, b.z, b.w};
        #pragma unroll
        for (int r = 0; r < 4; r++)
            #pragma unroll
            for (int c = 0; c < 4; c++) acc[r][c] += av[r] * bv[c];
    }
    #pragma unroll
    for (int r = 0; r < 4; r++)
        #pragma unroll
        for (int c = 0; c < 4; c++) {
            int col = n0 + tn * 4 + c;
            outp[(size_t)(m0 + tm * 4 + r) * D_ + col] = acc[r][c] + b_in[col];
        }
}

// ---------------------------------------------------------------------------
// GEMM: C[M][N] = A[M][K] @ BT[N][K] + bias (bf16 in, LDS chunk-swizzled)
// BK=64. Y-fast 1D grid: y = bx & 127, x = bx >> 7 (same-row blocks co-XCD).
// EPI: 0 = bf16, 1 = bf16+GELU, 2 = fp32 direct, 3 = fp16
// u16 outputs (EPI 0/1/3) go through an LDS-staged coalesced store (16B/lane).
// SPLITK: gridDim.z==2; z=0 -> C(+bias), z=1 -> C2 (no bias), both fp16.
// ---------------------------------------------------------------------------
template <int EPI, int TN, bool SPLITK>
__global__ __launch_bounds__(256) void gemm_bt_kernel(
    const u16* __restrict__ A, const u16* __restrict__ BT,
    const float* __restrict__ bias, void* __restrict__ C,
    void* __restrict__ C2, int M, int N, int K, int kLen)
{
    constexpr int NI = TN / 32;               // acc tiles per wave in N
    constexpr int NB = TN / 32;               // B staging chunks per thread
    __shared__ __align__(16) u16 smem[128 * 64 + TN * 64];
    u16* As = smem;
    u16* Bs = smem + 128 * 64;
    int bx = blockIdx.x;
    int m0 = (bx & 127) * 128, n0 = (bx >> 7) * TN;
    int z = SPLITK ? blockIdx.z : 0;
    int kStart = z * kLen;
    int t = threadIdx.x;
    int lane = t & 63, w = t >> 6;
    int wm = w >> 1, wn = w & 1;
    int l15 = lane & 15, quad = lane >> 4;

    // staging: rows of 8 chunks (16B each); LDS slot s in row r holds global
    // chunk s^(r&7). Lane-contiguous LDS dest (global_load_lds constraint).
    const u16* gA[4]; u16* lA[4];
    #pragma unroll
    for (int i = 0; i < 4; i++) {
        int ci = t + i * 256;                 // 1024 chunks of A
        int r = ci >> 3, s = ci & 7, gc = s ^ (r & 7);
        gA[i] = A + (size_t)(m0 + r) * K + kStart + gc * 8;
        lA[i] = &As[ci * 8];
    }
    const u16* gB[NB]; u16* lB[NB];
    #pragma unroll
    for (int i = 0; i < NB; i++) {
        int ci = t + i * 256;                 // TN*8 chunks of B
        int r = ci >> 3, s = ci & 7, gc = s ^ (r & 7);
        gB[i] = BT + (size_t)(n0 + r) * K + kStart + gc * 8;
        lB[i] = &Bs[ci * 8];
    }

    // fragment offsets (elements), per k-half
    int aoff[2][4], boff[2][NI];
    #pragma unroll
    for (int kh = 0; kh < 2; kh++) {
        #pragma unroll
        for (int mi = 0; mi < 4; mi++) {
            int row = wm * 64 + mi * 16 + l15;
            aoff[kh][mi] = row * 64 + (((kh * 4 + quad) ^ (row & 7)) * 8);
        }
        #pragma unroll
        for (int ni = 0; ni < NI; ni++) {
            int row = wn * (TN / 2) + ni * 16 + l15;
            boff[kh][ni] = row * 64 + (((kh * 4 + quad) ^ (row & 7)) * 8);
        }
    }

    f32x4 acc[4][NI];
    f32x4 zero = {0.f, 0.f, 0.f, 0.f};
    #pragma unroll
    for (int mi = 0; mi < 4; mi++)
        #pragma unroll
        for (int ni = 0; ni < NI; ni++) acc[mi][ni] = zero;

    for (int kk = 0; kk < kLen; kk += 64) {
        __syncthreads();
        #pragma unroll
        for (int i = 0; i < 4; i++) { gld_lds16(gA[i], lA[i]); gA[i] += 64; }
        #pragma unroll
        for (int i = 0; i < NB; i++) { gld_lds16(gB[i], lB[i]); gB[i] += 64; }
        __syncthreads();
        #pragma unroll
        for (int kh = 0; kh < 2; kh++) {
            bf16x8 a[4], b[NI];
            #pragma unroll
            for (int mi = 0; mi < 4; mi++)
                a[mi] = *(const bf16x8*)&As[aoff[kh][mi]];
            #pragma unroll
            for (int ni = 0; ni < NI; ni++)
                b[ni] = *(const bf16x8*)&Bs[boff[kh][ni]];
            #pragma unroll
            for (int mi = 0; mi < 4; mi++)
                #pragma unroll
                for (int ni = 0; ni < NI; ni++)
                    acc[mi][ni] = __builtin_amdgcn_mfma_f32_16x16x32_bf16(
                        a[mi], b[ni], acc[mi][ni], 0, 0, 0);
        }
    }

    bool partial = SPLITK && (z == 1);
    if (EPI == 2) {
        // direct fp32 stores (64B row segments — sector-sized, no ghost)
        #pragma unroll
        for (int ni = 0; ni < NI; ni++) {
            int col = n0 + wn * (TN / 2) + ni * 16 + l15;
            float bv = partial ? 0.f : bias[col];
            #pragma unroll
            for (int mi = 0; mi < 4; mi++) {
                int rbase = m0 + wm * 64 + mi * 16 + quad * 4;
                f32x4 v = acc[mi][ni];
                #pragma unroll
                for (int r = 0; r < 4; r++)
                    ((float*)C)[(size_t)(rbase + r) * N + col] = v[r] + bv;
            }
        }
    } else {
        // LDS-staged coalesced u16 store
        __syncthreads();
        u16* Ct = smem;   // 128*TN u16, fits in As(+Bs)
        #pragma unroll
        for (int ni = 0; ni < NI; ni++) {
            int colt = wn * (TN / 2) + ni * 16 + l15;      // tile-local col
            float bv = partial ? 0.f : bias[n0 + colt];
            #pragma unroll
            for (int mi = 0; mi < 4; mi++) {
                int rbase = wm * 64 + mi * 16 + quad * 4;  // tile-local row
                f32x4 v = acc[mi][ni];
                #pragma unroll
                for (int r = 0; r < 4; r++) {
                    float y = v[r] + bv;
                    if (EPI == 1) y = gelu_f(y);
                    u16 hv = (EPI == 3) ? f2h(y) : f2bf(y);
                    int row = rbase + r;
                    int cc = colt >> 3;
                    Ct[row * TN + (((cc ^ (row & 7)) * 8) | (colt & 7))] = hv;
                }
            }
        }
        __syncthreads();
        u16* dst = partial ? (u16*)C2 : (u16*)C;
        constexpr int CPR = TN / 8;
        #pragma unroll
        for (int i = 0; i < TN / 16; i++) {
            int ch = t + i * 256;
            int row = ch / CPR, cc = ch % CPR;
            uint4 vv = *(const uint4*)&Ct[row * TN + ((cc ^ (row & 7)) * 8)];
            *(uint4*)(dst + (size_t)(m0 + row) * N + n0 + cc * 8) = vv;
        }
    }
}

// ---------------------------------------------------------------------------
// Attention on fused qkv [NTOK][1536]. Block = (b,h,64 q rows). LDS swizzled.
// ---------------------------------------------------------------------------
__global__ __launch_bounds__(256) void attn_kernel(
    const u16* __restrict__ qkv, u16* __restrict__ o)
{
    __shared__ __align__(16) u16 kvs[S_ * HD_];      // 32 KB: K rows, then V^T
    __shared__ __align__(16) u16 P[4 * 16 * S_];     // 32 KB: per-wave probs
    int bx = blockIdx.x;
    int qc = bx & 3;
    int h = (bx >> 2) & 7;
    int b = bx >> 5;
    int t = threadIdx.x;
    int lane = t & 63, w = t >> 6;
    int l15 = lane & 15, quad = lane >> 4;
    size_t rowb = (size_t)b * S_;

    // stage K rows, chunk-swizzled: row t, chunk j at slot j^(t&7)
    {
        const u16* src = qkv + (rowb + t) * QKV3 + D_ + h * HD_;
        int sw = t & 7;
        #pragma unroll
        for (int j = 0; j < 8; j++)
            *(uint4*)&kvs[t * HD_ + ((j ^ sw) * 8)] = *(const uint4*)(src + j * 8);
    }
    bf16x8 aQ[2];
    {
        int qrow = qc * 64 + w * 16 + l15;
        const u16* src = qkv + (rowb + qrow) * QKV3 + h * HD_ + quad * 8;
        aQ[0] = *(const bf16x8*)(src);
        aQ[1] = *(const bf16x8*)(src + 32);
    }
    __syncthreads();

    // phase 1: S = Q K^T  (wave computes 16 x 256)
    f32x4 sc[16];
    #pragma unroll
    for (int nc = 0; nc < 16; nc++) {
        f32x4 acc = {0.f, 0.f, 0.f, 0.f};
        int row = nc * 16 + l15;
        int s0 = quad ^ (row & 7);
        bf16x8 b0 = *(const bf16x8*)&kvs[row * HD_ + s0 * 8];
        bf16x8 b1 = *(const bf16x8*)&kvs[row * HD_ + (s0 ^ 4) * 8];
        acc = __builtin_amdgcn_mfma_f32_16x16x32_bf16(aQ[0], b0, acc, 0, 0, 0);
        acc = __builtin_amdgcn_mfma_f32_16x16x32_bf16(aQ[1], b1, acc, 0, 0, 0);
        sc[nc] = acc;
    }
    const float scale = 0.125f;  // 1/sqrt(64)
    float rmax[4], rinv[4];
    #pragma unroll
    for (int r = 0; r < 4; r++) {
        float mx = -1e30f;
        #pragma unroll
        for (int nc = 0; nc < 16; nc++) mx = fmaxf(mx, sc[nc][r]);
        for (int off = 1; off < 16; off <<= 1) mx = fmaxf(mx, __shfl_xor(mx, off));
        rmax[r] = mx * scale;
    }
    #pragma unroll
    for (int r = 0; r < 4; r++) {
        float sum = 0.f;
        #pragma unroll
        for (int nc = 0; nc < 16; nc++) {
            float p = __expf(sc[nc][r] * scale - rmax[r]);
            sc[nc][r] = p;
            sum += p;
        }
        for (int off = 1; off < 16; off <<= 1) sum += __shfl_xor(sum, off);
        rinv[r] = 1.0f / sum;
    }
    // P store (bf16), chunk-swizzled per row
    #pragma unroll
    for (int nc = 0; nc < 16; nc++)
        #pragma unroll
        for (int r = 0; r < 4; r++) {
            int prow = quad * 4 + r;
            int col = nc * 16 + l15;
            int slot = (col >> 3) ^ (prow & 7);
            P[w * 4096 + prow * 256 + slot * 8 + (col & 7)] =
                f2bf(sc[nc][r] * rinv[r]);
        }
    __syncthreads();  // all waves done reading K + writing P

    // stage V^T[64 d][256 s], chunk-swizzled: row d, chunk c at slot c^(d&7)
    {
        const u16* src = qkv + (rowb + t) * QKV3 + 2 * D_ + h * HD_;
        int chunkc = t >> 3, bytec = t & 7;
        #pragma unroll
        for (int dj = 0; dj < 8; dj++) {
            uint4 x = *(const uint4*)(src + dj * 8);
            const u16* xs = (const u16*)&x;
            #pragma unroll
            for (int i = 0; i < 8; i++) {
                int vrow = dj * 8 + i;
                kvs[vrow * 256 + ((chunkc ^ (vrow & 7)) * 8) + bytec] = xs[i];
            }
        }
    }
    __syncthreads();

    // phase 2: O = P @ V   (wave: 16 x 64)
    f32x4 accO[4];
    f32x4 zero = {0.f, 0.f, 0.f, 0.f};
    #pragma unroll
    for (int nt = 0; nt < 4; nt++) accO[nt] = zero;
    for (int ks = 0; ks < 8; ks++) {
        int ch = ks * 4 + quad;
        bf16x8 aP = *(const bf16x8*)&P[w * 4096 + l15 * 256 + ((ch ^ (l15 & 7)) * 8)];
        #pragma unroll
        for (int nt = 0; nt < 4; nt++) {
            int vrow = nt * 16 + l15;
            bf16x8 bV = *(const bf16x8*)&kvs[vrow * 256 + ((ch ^ (vrow & 7)) * 8)];
            accO[nt] = __builtin_amdgcn_mfma_f32_16x16x32_bf16(aP, bV, accO[nt], 0, 0, 0);
        }
    }
    // O through LDS (reuse P) -> coalesced 16B stores, 128B row segments
    __syncthreads();
    u16* Ot = P;     // 64 x 64 u16
    #pragma unroll
    for (int nt = 0; nt < 4; nt++)
        #pragma unroll
        for (int r = 0; r < 4; r++) {
            int row = w * 16 + quad * 4 + r;
            int col = nt * 16 + l15;
            int cc = col >> 3;
            Ot[row * 64 + (((cc ^ (row & 7)) * 8) | (col & 7))] = f2bf(accO[nt][r]);
        }
    __syncthreads();
    #pragma unroll
    for (int i = 0; i < 2; i++) {
        int ch = t + i * 256;
        int row = ch >> 3, cc = ch & 7;
        uint4 vv = *(const uint4*)&Ot[row * 64 + ((cc ^ (row & 7)) * 8)];
        *(uint4*)(o + (rowb + qc * 64 + row) * D_ + h * HD_ + cc * 8) = vv;
    }
}

// ---------------------------------------------------------------------------
// LayerNorm: out = LN(in [+ in2] [+ res]) * g + b, optional GELU / PE.
// INK: 0 = fp32 inputs, 1 = fp16 inputs.
// ---------------------------------------------------------------------------
template <int WIDTH, int INK, bool RES, bool GELU, bool PE, bool SUM2>
__global__ __launch_bounds__(WIDTH) void ln_kernel(
    const void* __restrict__ in, const void* __restrict__ in2,
    const u16* __restrict__ res,
    const float* __restrict__ g, const float* __restrict__ b,
    u16* __restrict__ out)
{
    __shared__ float rs[8], rq[8];
    int row = blockIdx.x;
    int t = threadIdx.x;
    size_t base = (size_t)row * WIDTH;
    float v = (INK == 0) ? ((const float*)in)[base + t]
                         : h2f(((const u16*)in)[base + t]);
    if (SUM2) v += (INK == 0) ? ((const float*)in2)[base + t]
                              : h2f(((const u16*)in2)[base + t]);
    if (RES) v += bf2f(res[base + t]);
    float sm = v, sq = v * v;
    for (int off = 32; off; off >>= 1) {
        sm += __shfl_xor(sm, off);
        sq += __shfl_xor(sq, off);
    }
    constexpr int NW = WIDTH / 64;
    if ((t & 63) == 0) { rs[t >> 6] = sm; rq[t >> 6] = sq; }
    __syncthreads();
    float ts = 0.f, tq = 0.f;
    #pragma unroll
    for (int i = 0; i < NW; i++) { ts += rs[i]; tq += rq[i]; }
    float mean = ts / (float)WIDTH;
    float var = tq / (float)WIDTH - mean * mean;
    float rstd = rsqrtf(var + 1e-5f);
    float y = (v - mean) * rstd * g[t] + b[t];
    if (GELU) y = gelu_f(y);
    if (PE) {
        const float c = -9.210340371976184f / (float)D_;  // -ln(10000)/D
        int s = row & (S_ - 1);
        int i2 = t >> 1;
        float ang = (float)s * __expf((float)(2 * i2) * c);
        y += (t & 1) ? __cosf(ang) : __sinf(ang);
    }
    out[base + t] = f2bf(y);
}

// ---------------------------------------------------------------------------
// Head: out = tanh(y2 @ Wp3 + bp3) * scale + bias. 8 rows x 32 cols per block.
// ---------------------------------------------------------------------------
__global__ __launch_bounds__(256) void head_kernel(
    const u16* __restrict__ y2, const float* __restrict__ W,
    const float* __restrict__ bias, const float* __restrict__ scl,
    const float* __restrict__ bs, float* __restrict__ out)
{
    __shared__ float Ws[128 * ACT_];
    __shared__ u16 Ys[8 * 128];
    int t = threadIdx.x;
    for (int i = t; i < 128 * ACT_; i += 256) Ws[i] = W[i];
    int r0 = blockIdx.x * 8;
    for (int i = t; i < 8 * 128; i += 256) Ys[i] = y2[(size_t)r0 * 128 + i];
    __syncthreads();
    int lr = t >> 5, c = t & 31;
    if (c < ACT_) {
        float acc = bias[c];
        for (int kk = 0; kk < 128; kk++)
            acc += bf2f(Ys[lr * 128 + kk]) * Ws[kk * ACT_ + c];
        float y = tanhf(acc);
        out[(size_t)(r0 + lr) * ACT_ + c] = y * scl[c] + bs[c];
    }
}

// ---------------------------------------------------------------------------
extern "C" void kernel_launch(void* const* d_in, const int* in_sizes, int n_in,
                              void* d_out, int out_size, void* d_ws, size_t ws_size,
                              hipStream_t stream)
{
    const float* obs   = (const float*)d_in[0];
    const float* W_in  = (const float*)d_in[1];
    const float* b_in  = (const float*)d_in[2];
    const float* g_in  = (const float*)d_in[3];
    const float* be_in = (const float*)d_in[4];
    const float* Wq  = (const float*)d_in[5];
    const float* bq  = (const float*)d_in[6];
    const float* Wk  = (const float*)d_in[7];
    const float* bk  = (const float*)d_in[8];
    const float* Wv  = (const float*)d_in[9];
    const float* bv  = (const float*)d_in[10];
    const float* Wo  = (const float*)d_in[11];
    const float* bo  = (const float*)d_in[12];
    const float* g1  = (const float*)d_in[13];
    const float* be1 = (const float*)d_in[14];
    const float* W1  = (const float*)d_in[15];
    const float* b1  = (const float*)d_in[16];
    const float* W2  = (const float*)d_in[17];
    const float* b2  = (const float*)d_in[18];
    const float* g2  = (const float*)d_in[19];
    const float* be2 = (const float*)d_in[20];
    const float* Wp1  = (const float*)d_in[21];
    const float* bp1  = (const float*)d_in[22];
    const float* gp1  = (const float*)d_in[23];
    const float* bep1 = (const float*)d_in[24];
    const float* Wp2  = (const float*)d_in[25];
    const float* bp2  = (const float*)d_in[26];
    const float* gp2  = (const float*)d_in[27];
    const float* bep2 = (const float*)d_in[28];
    const float* Wp3  = (const float*)d_in[29];
    const float* bp3  = (const float*)d_in[30];
    const float* ascl = (const float*)d_in[31];
    const float* abias = (const float*)d_in[32];

    char* ws = (char*)d_ws;
    size_t off = 0;
    auto alloc = [&](size_t bytes) {
        void* p = ws + off;
        off += (bytes + 255) & ~(size_t)255;
        return p;
    };
    u16* WQKVT = (u16*)alloc((size_t)L_ * QKV3 * D_ * 2);     // 12.6 MB
    u16* WOT   = (u16*)alloc((size_t)L_ * D_ * D_ * 2);       // 4 MB
    u16* W1T   = (u16*)alloc((size_t)L_ * D_ * FF_ * 2);      // 16 MB
    u16* W2T   = (u16*)alloc((size_t)L_ * FF_ * D_ * 2);      // 16 MB
    u16* WP1T  = (u16*)alloc((size_t)D_ * (D_ / 2) * 2);
    u16* WP2T  = (u16*)alloc((size_t)(D_ / 2) * (D_ / 4) * 2);
    float* bqkv = (float*)alloc((size_t)L_ * QKV3 * 4);
    u16* x_bf = (u16*)alloc((size_t)NTOK * D_ * 2);           // 16 MB
    float* tmp = (float*)alloc((size_t)NTOK * D_ * 4);        // 32 MB (f32 or f16 use)
    char* regionA = (char*)alloc((size_t)NTOK * FF_ * 2);     // 64 MB
    size_t base_need = off;
    char* tmp2 = ws + base_need;                              // +16 MB if fits
    bool split = (ws_size >= base_need + (size_t)NTOK * D_ * 2);
    (void)in_sizes; (void)n_in; (void)out_size;

    u16* qkvbuf = (u16*)(regionA);                            // 48 MB
    u16* obuf = (u16*)(regionA + (size_t)NTOK * QKV3 * 2);    // 16 MB
    u16* hbuf = (u16*)(regionA);                              // 64 MB (aliases)
    // head-phase aliases (regionA free then)
    u16* y1_bf = (u16*)(regionA);                             // 8 MB
    u16* y2_bf = (u16*)(regionA + (32u << 20));               // 4 MB

    dim3 tb(32, 8);
    size_t DD = (size_t)D_ * D_;
    transpose_bf16_kernel<<<dim3(16, 16, L_), tb, 0, stream>>>(
        Wq, WQKVT, D_, D_, DD, (size_t)QKV3 * D_);
    transpose_bf16_kernel<<<dim3(16, 16, L_), tb, 0, stream>>>(
        Wk, WQKVT + DD, D_, D_, DD, (size_t)QKV3 * D_);
    transpose_bf16_kernel<<<dim3(16, 16, L_), tb, 0, stream>>>(
        Wv, WQKVT + 2 * DD, D_, D_, DD, (size_t)QKV3 * D_);
    transpose_bf16_kernel<<<dim3(16, 16, L_), tb, 0, stream>>>(
        Wo, WOT, D_, D_, DD, DD);
    transpose_bf16_kernel<<<dim3(64, 16, L_), tb, 0, stream>>>(
        W1, W1T, D_, FF_, (size_t)D_ * FF_, (size_t)D_ * FF_);
    transpose_bf16_kernel<<<dim3(16, 64, L_), tb, 0, stream>>>(
        W2, W2T, FF_, D_, (size_t)D_ * FF_, (size_t)D_ * FF_);
    transpose_bf16_kernel<<<dim3(8, 16, 1), tb, 0, stream>>>(
        Wp1, WP1T, D_, D_ / 2, 0, 0);
    transpose_bf16_kernel<<<dim3(4, 8, 1), tb, 0, stream>>>(
        Wp2, WP2T, D_ / 2, D_ / 4, 0, 0);
    concat_bias_kernel<<<L_ * QKV3 / 256, 256, 0, stream>>>(bq, bk, bv, bqkv);

    in_gemm_kernel<<<dim3(D_ / 64, NTOK / 64), 256, 0, stream>>>(
        obs, W_in, b_in, tmp);
    ln_kernel<D_, 0, false, true, true, false><<<NTOK, D_, 0, stream>>>(
        tmp, nullptr, nullptr, g_in, be_in, x_bf);

    const int MG = NTOK / 128;  // 128 M-blocks; grid = 128 * NX (y-fast)
    for (int l = 0; l < L_; l++) {
        const u16* wqkvt = WQKVT + (size_t)l * QKV3 * D_;
        const u16* wot = WOT + (size_t)l * DD;
        const u16* w1t = W1T + (size_t)l * D_ * FF_;
        const u16* w2t = W2T + (size_t)l * FF_ * D_;

        gemm_bt_kernel<0, 128, false><<<MG * (QKV3 / 128), 256, 0, stream>>>(
            x_bf, wqkvt, bqkv + l * QKV3, qkvbuf, nullptr, NTOK, QKV3, D_, D_);
        attn_kernel<<<B_ * H_ * (S_ / 64), 256, 0, stream>>>(qkvbuf, obuf);
        if (split) {
            gemm_bt_kernel<3, 128, true><<<dim3(MG * 4, 1, 2), 256, 0, stream>>>(
                obuf, wot, bo + l * D_, tmp, tmp2, NTOK, D_, D_, D_ / 2);
            ln_kernel<D_, 1, true, false, false, true><<<NTOK, D_, 0, stream>>>(
                tmp, tmp2, x_bf, g1 + l * D_, be1 + l * D_, x_bf);
        } else {
            gemm_bt_kernel<2, 128, false><<<MG * 4, 256, 0, stream>>>(
                obuf, wot, bo + l * D_, tmp, nullptr, NTOK, D_, D_, D_);
            ln_kernel<D_, 0, true, false, false, false><<<NTOK, D_, 0, stream>>>(
                tmp, nullptr, x_bf, g1 + l * D_, be1 + l * D_, x_bf);
        }
        gemm_bt_kernel<1, 128, false><<<MG * (FF_ / 128), 256, 0, stream>>>(
            x_bf, w1t, b1 + l * FF_, hbuf, nullptr, NTOK, FF_, D_, D_);
        if (split) {
            gemm_bt_kernel<3, 128, true><<<dim3(MG * 4, 1, 2), 256, 0, stream>>>(
                hbuf, w2t, b2 + l * D_, tmp, tmp2, NTOK, D_, FF_, FF_ / 2);
            ln_kernel<D_, 1, true, false, false, true><<<NTOK, D_, 0, stream>>>(
                tmp, tmp2, x_bf, g2 + l * D_, be2 + l * D_, x_bf);
        } else {
            gemm_bt_kernel<2, 128, false><<<MG * 4, 256, 0, stream>>>(
                hbuf, w2t, b2 + l * D_, tmp, nullptr, NTOK, D_, FF_, FF_);
            ln_kernel<D_, 0, true, false, false, false><<<NTOK, D_, 0, stream>>>(
                tmp, nullptr, x_bf, g2 + l * D_, be2 + l * D_, x_bf);
        }
    }

    // policy head
    if (split) {
        gemm_bt_kernel<3, 64, true><<<dim3(MG * 4, 1, 2), 256, 0, stream>>>(
            x_bf, WP1T, bp1, tmp, tmp2, NTOK, D_ / 2, D_, D_ / 2);
        ln_kernel<D_ / 2, 1, false, true, false, true><<<NTOK, D_ / 2, 0, stream>>>(
            tmp, tmp2, nullptr, gp1, bep1, y1_bf);
        gemm_bt_kernel<3, 64, true><<<dim3(MG * 2, 1, 2), 256, 0, stream>>>(
            y1_bf, WP2T, bp2, tmp, tmp2, NTOK, D_ / 4, D_ / 2, D_ / 4);
        ln_kernel<D_ / 4, 1, false, true, false, true><<<NTOK, D_ / 4, 0, stream>>>(
            tmp, tmp2, nullptr, gp2, bep2, y2_bf);
    } else {
        gemm_bt_kernel<2, 64, false><<<MG * 4, 256, 0, stream>>>(
            x_bf, WP1T, bp1, tmp, nullptr, NTOK, D_ / 2, D_, D_);
        ln_kernel<D_ / 2, 0, false, true, false, false><<<NTOK, D_ / 2, 0, stream>>>(
            tmp, nullptr, nullptr, gp1, bep1, y1_bf);
        gemm_bt_kernel<2, 64, false><<<MG * 2, 256, 0, stream>>>(
            y1_bf, WP2T, bp2, tmp, nullptr, NTOK, D_ / 4, D_ / 2, D_ / 2);
        ln_kernel<D_ / 4, 0, false, true, false, false><<<NTOK, D_ / 4, 0, stream>>>(
            tmp, nullptr, nullptr, gp2, bep2, y2_bf);
    }
    head_kernel<<<NTOK / 8, 256, 0, stream>>>(
        y2_bf, Wp3, bp3, ascl, abias, (float*)d_out);
}

// Round 8
// 2193.586 us; speedup vs baseline: 1.2399x; 1.0833x over previous
//
#include <hip/hip_runtime.h>

typedef unsigned short u16;
typedef unsigned int u32;
typedef __attribute__((ext_vector_type(8))) __bf16 bf16x8;
typedef __attribute__((ext_vector_type(4))) float f32x4;

#define B_ 64
#define S_ 256
#define OBS_ 96
#define ACT_ 29
#define D_ 512
#define H_ 8
#define L_ 8
#define FF_ 2048
#define HD_ 64
#define NTOK (B_ * S_)   // 16384
#define QKV3 (3 * D_)    // 1536

__device__ __forceinline__ u16 f2bf(float f) {
    u32 u = __float_as_uint(f);
    u += 0x7FFFu + ((u >> 16) & 1u);
    return (u16)(u >> 16);
}
__device__ __forceinline__ float bf2f(u16 h) {
    return __uint_as_float(((u32)h) << 16);
}
__device__ __forceinline__ u16 f2h(float f) {
    _Float16 h = (_Float16)f;
    u16 u; __builtin_memcpy(&u, &h, 2); return u;
}
__device__ __forceinline__ float h2f(u16 u) {
    _Float16 h; __builtin_memcpy(&h, &u, 2); return (float)h;
}
// 7-inst GELU: x*sigmoid(2z), z = 0.79788456(x+0.044715x^3), exp2/rcp form.
__device__ __forceinline__ float gelu_f(float x) {
    const float k1 = 2.3022121f;    // 2*0.79788456*log2(e)
    const float k2 = 0.10294451f;   // k1*0.044715
    float x2 = x * x;
    float arg = x * __builtin_fmaf(x2, k2, k1);
    float e = exp2f(arg);
    float r = __builtin_amdgcn_rcpf(1.0f + e);
    return __builtin_fmaf(-x, r, x);
}
// async global->LDS, 16B per lane. LDS dest is wave-uniform base + lane*16.
__device__ __forceinline__ void gld_lds16(const u16* g, u16* l) {
    __builtin_amdgcn_global_load_lds(
        (const __attribute__((address_space(1))) unsigned int*)g,
        (__attribute__((address_space(3))) unsigned int*)l, 16, 0, 0);
}

// ---------------------------------------------------------------------------
// Transpose + downcast: src fp32 [z][K][N] -> dst bf16 [z][N][K] (strided)
// ---------------------------------------------------------------------------
__global__ __launch_bounds__(256) void transpose_bf16_kernel(
    const float* __restrict__ src, u16* __restrict__ dst, int K, int N,
    size_t srcStride, size_t dstStride)
{
    __shared__ float tile[32][33];
    int n0 = blockIdx.x * 32, k0 = blockIdx.y * 32;
    const float* s = src + (size_t)blockIdx.z * srcStride;
    u16* d = dst + (size_t)blockIdx.z * dstStride;
    int tx = threadIdx.x, ty = threadIdx.y;   // block (32,8)
    for (int i = 0; i < 32; i += 8)
        tile[ty + i][tx] = s[(size_t)(k0 + ty + i) * N + n0 + tx];
    __syncthreads();
    for (int i = 0; i < 32; i += 8)
        d[(size_t)(n0 + ty + i) * K + k0 + tx] = f2bf(tile[tx][ty + i]);
}

__global__ __launch_bounds__(256) void concat_bias_kernel(
    const float* __restrict__ bq, const float* __restrict__ bk,
    const float* __restrict__ bv, float* __restrict__ dst)
{
    int i = blockIdx.x * 256 + threadIdx.x;      // over L*1536
    int l = i / QKV3, r = i - l * QKV3;
    float v;
    if (r < D_)            v = bq[l * D_ + r];
    else if (r < 2 * D_)   v = bk[l * D_ + r - D_];
    else                   v = bv[l * D_ + r - 2 * D_];
    dst[i] = v;
}

// ---------------------------------------------------------------------------
// Input projection GEMM (fp32): outp[M][512] = obs[M][96] @ Win[96][512] + b
// ---------------------------------------------------------------------------
__global__ __launch_bounds__(256) void in_gemm_kernel(
    const float* __restrict__ obs, const float* __restrict__ Win,
    const float* __restrict__ b_in, float* __restrict__ outp)
{
    __shared__ float As[OBS_][68];
    __shared__ float Bs[OBS_][68];
    int m0 = blockIdx.y * 64, n0 = blockIdx.x * 64;
    int t = threadIdx.x;
    #pragma unroll
    for (int i = 0; i < 24; i++) {
        int idx = i * 256 + t;
        int m = idx / OBS_, kk = idx - m * OBS_;
        As[kk][m] = obs[(size_t)(m0 + m) * OBS_ + kk];
    }
    #pragma unroll
    for (int i = 0; i < 24; i++) {
        int idx = i * 256 + t;
        int kk = idx >> 6, n = idx & 63;
        Bs[kk][n] = Win[(size_t)kk * D_ + n0 + n];
    }
    __syncthreads();
    int tm = t >> 4, tn = t & 15;
    float acc[4][4] = {};
    for (int kk = 0; kk < OBS_; kk++) {
        float4 a = *(const float4*)&As[kk][tm * 4];
        float4 b = *(const float4*)&Bs[kk][tn * 4];
        const float av[4] = {a.x, a.y, a.z, a.w};
        const float bv[4] = {b.x, b.y, b.z, b.w};
        #pragma unroll
        for (int r = 0; r < 4; r++)
            #pragma unroll
            for (int c = 0; c < 4; c++) acc[r][c] += av[r] * bv[c];
    }
    #pragma unroll
    for (int r = 0; r < 4; r++)
        #pragma unroll
        for (int c = 0; c < 4; c++) {
            int col = n0 + tn * 4 + c;
            outp[(size_t)(m0 + tm * 4 + r) * D_ + col] = acc[r][c] + b_in[col];
        }
}

// ---------------------------------------------------------------------------
// GEMM: C[M][N] = A[M][K] @ BT[N][K] + bias (bf16 in, LDS chunk-swizzled)
// BK=64. Y-fast 1D grid: y = bx & 127, x = bx >> 7 (same-row blocks co-XCD).
// Staging addressing: ONE per-thread 32-bit offset set (A and B share chunk
// geometry); uniform SGPR bases advance per iter. Register diet for 3 w/EU.
// EPI: 0 = bf16, 1 = bf16+GELU, 2 = fp32 direct, 3 = fp16
// u16 outputs (EPI 0/1/3) go through an LDS-staged coalesced store (16B/lane).
// SPLITK: gridDim.z==2; z=0 -> C(+bias), z=1 -> C2 (no bias), both fp16.
// ---------------------------------------------------------------------------
template <int EPI, int TN, bool SPLITK>
__global__ __launch_bounds__(256, 3) void gemm_bt_kernel(
    const u16* __restrict__ A, const u16* __restrict__ BT,
    const float* __restrict__ bias, void* __restrict__ C,
    void* __restrict__ C2, int M, int N, int K, int kLen)
{
    constexpr int NI = TN / 32;               // acc tiles per wave in N
    constexpr int NB = TN / 32;               // B staging chunks per thread
    __shared__ __align__(16) u16 smem[128 * 64 + TN * 64];
    u16* As = smem;
    u16* Bs = smem + 128 * 64;
    int bx = blockIdx.x;
    int m0 = (bx & 127) * 128, n0 = (bx >> 7) * TN;
    int z = SPLITK ? blockIdx.z : 0;
    int kStart = z * kLen;
    int t = threadIdx.x;
    int lane = t & 63, w = t >> 6;
    int wm = w >> 1, wn = w & 1;
    int l15 = lane & 15, quad = lane >> 4;

    // staging geometry: chunk ci -> row r = ci>>3, LDS slot s = ci&7 holds
    // global chunk s^(r&7). Same per-thread offsets serve A and B.
    int offC[4]; u16* lA[4];
    #pragma unroll
    for (int i = 0; i < 4; i++) {
        int ci = t + i * 256;
        int r = ci >> 3, s = ci & 7, gc = s ^ (r & 7);
        offC[i] = r * K + gc * 8;
        lA[i] = &As[ci * 8];
    }
    const u16* Abase = A + (size_t)m0 * K + kStart;
    const u16* Bbase = BT + (size_t)n0 * K + kStart;

    // fragment offsets (elements), per k-half
    int aoff[2][4], boff[2][NI];
    #pragma unroll
    for (int kh = 0; kh < 2; kh++) {
        #pragma unroll
        for (int mi = 0; mi < 4; mi++) {
            int row = wm * 64 + mi * 16 + l15;
            aoff[kh][mi] = row * 64 + (((kh * 4 + quad) ^ (row & 7)) * 8);
        }
        #pragma unroll
        for (int ni = 0; ni < NI; ni++) {
            int row = wn * (TN / 2) + ni * 16 + l15;
            boff[kh][ni] = row * 64 + (((kh * 4 + quad) ^ (row & 7)) * 8);
        }
    }

    f32x4 acc[4][NI];
    f32x4 zero = {0.f, 0.f, 0.f, 0.f};
    #pragma unroll
    for (int mi = 0; mi < 4; mi++)
        #pragma unroll
        for (int ni = 0; ni < NI; ni++) acc[mi][ni] = zero;

    for (int kk = 0; kk < kLen; kk += 64) {
        __syncthreads();
        #pragma unroll
        for (int i = 0; i < 4; i++) gld_lds16(Abase + offC[i], lA[i]);
        #pragma unroll
        for (int i = 0; i < NB; i++) gld_lds16(Bbase + offC[i], lA[i] + 128 * 64);
        Abase += 64; Bbase += 64;
        __syncthreads();
        #pragma unroll
        for (int kh = 0; kh < 2; kh++) {
            bf16x8 a[4], b[NI];
            #pragma unroll
            for (int mi = 0; mi < 4; mi++)
                a[mi] = *(const bf16x8*)&As[aoff[kh][mi]];
            #pragma unroll
            for (int ni = 0; ni < NI; ni++)
                b[ni] = *(const bf16x8*)&Bs[boff[kh][ni]];
            #pragma unroll
            for (int mi = 0; mi < 4; mi++)
                #pragma unroll
                for (int ni = 0; ni < NI; ni++)
                    acc[mi][ni] = __builtin_amdgcn_mfma_f32_16x16x32_bf16(
                        a[mi], b[ni], acc[mi][ni], 0, 0, 0);
        }
    }

    bool partial = SPLITK && (z == 1);
    if (EPI == 2) {
        // direct fp32 stores (64B row segments — sector-sized, no ghost)
        #pragma unroll
        for (int ni = 0; ni < NI; ni++) {
            int col = n0 + wn * (TN / 2) + ni * 16 + l15;
            float bv = partial ? 0.f : bias[col];
            #pragma unroll
            for (int mi = 0; mi < 4; mi++) {
                int rbase = m0 + wm * 64 + mi * 16 + quad * 4;
                f32x4 v = acc[mi][ni];
                #pragma unroll
                for (int r = 0; r < 4; r++)
                    ((float*)C)[(size_t)(rbase + r) * N + col] = v[r] + bv;
            }
        }
    } else {
        // LDS-staged coalesced u16 store
        __syncthreads();
        u16* Ct = smem;   // 128*TN u16, fits in As(+Bs)
        #pragma unroll
        for (int ni = 0; ni < NI; ni++) {
            int colt = wn * (TN / 2) + ni * 16 + l15;      // tile-local col
            float bv = partial ? 0.f : bias[n0 + colt];
            #pragma unroll
            for (int mi = 0; mi < 4; mi++) {
                int rbase = wm * 64 + mi * 16 + quad * 4;  // tile-local row
                f32x4 v = acc[mi][ni];
                #pragma unroll
                for (int r = 0; r < 4; r++) {
                    float y = v[r] + bv;
                    if (EPI == 1) y = gelu_f(y);
                    u16 hv = (EPI == 3) ? f2h(y) : f2bf(y);
                    int row = rbase + r;
                    int cc = colt >> 3;
                    Ct[row * TN + (((cc ^ (row & 7)) * 8) | (colt & 7))] = hv;
                }
            }
        }
        __syncthreads();
        u16* dst = partial ? (u16*)C2 : (u16*)C;
        constexpr int CPR = TN / 8;
        #pragma unroll
        for (int i = 0; i < TN / 16; i++) {
            int ch = t + i * 256;
            int row = ch / CPR, cc = ch % CPR;
            uint4 vv = *(const uint4*)&Ct[row * TN + ((cc ^ (row & 7)) * 8)];
            *(uint4*)(dst + (size_t)(m0 + row) * N + n0 + cc * 8) = vv;
        }
    }
}

// ---------------------------------------------------------------------------
// Attention on fused qkv [NTOK][1536]. Block = (b,h,64 q rows). LDS swizzled.
// ---------------------------------------------------------------------------
__global__ __launch_bounds__(256) void attn_kernel(
    const u16* __restrict__ qkv, u16* __restrict__ o)
{
    __shared__ __align__(16) u16 kvs[S_ * HD_];      // 32 KB: K rows, then V^T
    __shared__ __align__(16) u16 P[4 * 16 * S_];     // 32 KB: per-wave probs
    int bx = blockIdx.x;
    int qc = bx & 3;
    int h = (bx >> 2) & 7;
    int b = bx >> 5;
    int t = threadIdx.x;
    int lane = t & 63, w = t >> 6;
    int l15 = lane & 15, quad = lane >> 4;
    size_t rowb = (size_t)b * S_;

    // stage K rows, chunk-swizzled: row t, chunk j at slot j^(t&7)
    {
        const u16* src = qkv + (rowb + t) * QKV3 + D_ + h * HD_;
        int sw = t & 7;
        #pragma unroll
        for (int j = 0; j < 8; j++)
            *(uint4*)&kvs[t * HD_ + ((j ^ sw) * 8)] = *(const uint4*)(src + j * 8);
    }
    bf16x8 aQ[2];
    {
        int qrow = qc * 64 + w * 16 + l15;
        const u16* src = qkv + (rowb + qrow) * QKV3 + h * HD_ + quad * 8;
        aQ[0] = *(const bf16x8*)(src);
        aQ[1] = *(const bf16x8*)(src + 32);
    }
    __syncthreads();

    // phase 1: S = Q K^T  (wave computes 16 x 256)
    f32x4 sc[16];
    #pragma unroll
    for (int nc = 0; nc < 16; nc++) {
        f32x4 acc = {0.f, 0.f, 0.f, 0.f};
        int row = nc * 16 + l15;
        int s0 = quad ^ (row & 7);
        bf16x8 b0 = *(const bf16x8*)&kvs[row * HD_ + s0 * 8];
        bf16x8 b1 = *(const bf16x8*)&kvs[row * HD_ + (s0 ^ 4) * 8];
        acc = __builtin_amdgcn_mfma_f32_16x16x32_bf16(aQ[0], b0, acc, 0, 0, 0);
        acc = __builtin_amdgcn_mfma_f32_16x16x32_bf16(aQ[1], b1, acc, 0, 0, 0);
        sc[nc] = acc;
    }
    const float scale = 0.125f;  // 1/sqrt(64)
    float rmax[4], rinv[4];
    #pragma unroll
    for (int r = 0; r < 4; r++) {
        float mx = -1e30f;
        #pragma unroll
        for (int nc = 0; nc < 16; nc++) mx = fmaxf(mx, sc[nc][r]);
        for (int off = 1; off < 16; off <<= 1) mx = fmaxf(mx, __shfl_xor(mx, off));
        rmax[r] = mx * scale;
    }
    #pragma unroll
    for (int r = 0; r < 4; r++) {
        float sum = 0.f;
        #pragma unroll
        for (int nc = 0; nc < 16; nc++) {
            float p = __expf(sc[nc][r] * scale - rmax[r]);
            sc[nc][r] = p;
            sum += p;
        }
        for (int off = 1; off < 16; off <<= 1) sum += __shfl_xor(sum, off);
        rinv[r] = 1.0f / sum;
    }
    // P store (bf16), chunk-swizzled per row
    #pragma unroll
    for (int nc = 0; nc < 16; nc++)
        #pragma unroll
        for (int r = 0; r < 4; r++) {
            int prow = quad * 4 + r;
            int col = nc * 16 + l15;
            int slot = (col >> 3) ^ (prow & 7);
            P[w * 4096 + prow * 256 + slot * 8 + (col & 7)] =
                f2bf(sc[nc][r] * rinv[r]);
        }
    __syncthreads();  // all waves done reading K + writing P

    // stage V^T[64 d][256 s], chunk-swizzled: row d, chunk c at slot c^(d&7)
    {
        const u16* src = qkv + (rowb + t) * QKV3 + 2 * D_ + h * HD_;
        int chunkc = t >> 3, bytec = t & 7;
        #pragma unroll
        for (int dj = 0; dj < 8; dj++) {
            uint4 x = *(const uint4*)(src + dj * 8);
            const u16* xs = (const u16*)&x;
            #pragma unroll
            for (int i = 0; i < 8; i++) {
                int vrow = dj * 8 + i;
                kvs[vrow * 256 + ((chunkc ^ (vrow & 7)) * 8) + bytec] = xs[i];
            }
        }
    }
    __syncthreads();

    // phase 2: O = P @ V   (wave: 16 x 64)
    f32x4 accO[4];
    f32x4 zero = {0.f, 0.f, 0.f, 0.f};
    #pragma unroll
    for (int nt = 0; nt < 4; nt++) accO[nt] = zero;
    for (int ks = 0; ks < 8; ks++) {
        int ch = ks * 4 + quad;
        bf16x8 aP = *(const bf16x8*)&P[w * 4096 + l15 * 256 + ((ch ^ (l15 & 7)) * 8)];
        #pragma unroll
        for (int nt = 0; nt < 4; nt++) {
            int vrow = nt * 16 + l15;
            bf16x8 bV = *(const bf16x8*)&kvs[vrow * 256 + ((ch ^ (vrow & 7)) * 8)];
            accO[nt] = __builtin_amdgcn_mfma_f32_16x16x32_bf16(aP, bV, accO[nt], 0, 0, 0);
        }
    }
    // O through LDS (reuse P) -> coalesced 16B stores, 128B row segments
    __syncthreads();
    u16* Ot = P;     // 64 x 64 u16
    #pragma unroll
    for (int nt = 0; nt < 4; nt++)
        #pragma unroll
        for (int r = 0; r < 4; r++) {
            int row = w * 16 + quad * 4 + r;
            int col = nt * 16 + l15;
            int cc = col >> 3;
            Ot[row * 64 + (((cc ^ (row & 7)) * 8) | (col & 7))] = f2bf(accO[nt][r]);
        }
    __syncthreads();
    #pragma unroll
    for (int i = 0; i < 2; i++) {
        int ch = t + i * 256;
        int row = ch >> 3, cc = ch & 7;
        uint4 vv = *(const uint4*)&Ot[row * 64 + ((cc ^ (row & 7)) * 8)];
        *(uint4*)(o + (rowb + qc * 64 + row) * D_ + h * HD_ + cc * 8) = vv;
    }
}

// ---------------------------------------------------------------------------
// LayerNorm: out = LN(in [+ in2] [+ res]) * g + b, optional GELU / PE.
// INK: 0 = fp32 inputs, 1 = fp16 inputs.
// ---------------------------------------------------------------------------
template <int WIDTH, int INK, bool RES, bool GELU, bool PE, bool SUM2>
__global__ __launch_bounds__(WIDTH) void ln_kernel(
    const void* __restrict__ in, const void* __restrict__ in2,
    const u16* __restrict__ res,
    const float* __restrict__ g, const float* __restrict__ b,
    u16* __restrict__ out)
{
    __shared__ float rs[8], rq[8];
    int row = blockIdx.x;
    int t = threadIdx.x;
    size_t base = (size_t)row * WIDTH;
    float v = (INK == 0) ? ((const float*)in)[base + t]
                         : h2f(((const u16*)in)[base + t]);
    if (SUM2) v += (INK == 0) ? ((const float*)in2)[base + t]
                              : h2f(((const u16*)in2)[base + t]);
    if (RES) v += bf2f(res[base + t]);
    float sm = v, sq = v * v;
    for (int off = 32; off; off >>= 1) {
        sm += __shfl_xor(sm, off);
        sq += __shfl_xor(sq, off);
    }
    constexpr int NW = WIDTH / 64;
    if ((t & 63) == 0) { rs[t >> 6] = sm; rq[t >> 6] = sq; }
    __syncthreads();
    float ts = 0.f, tq = 0.f;
    #pragma unroll
    for (int i = 0; i < NW; i++) { ts += rs[i]; tq += rq[i]; }
    float mean = ts / (float)WIDTH;
    float var = tq / (float)WIDTH - mean * mean;
    float rstd = rsqrtf(var + 1e-5f);
    float y = (v - mean) * rstd * g[t] + b[t];
    if (GELU) y = gelu_f(y);
    if (PE) {
        const float c = -9.210340371976184f / (float)D_;  // -ln(10000)/D
        int s = row & (S_ - 1);
        int i2 = t >> 1;
        float ang = (float)s * __expf((float)(2 * i2) * c);
        y += (t & 1) ? __cosf(ang) : __sinf(ang);
    }
    out[base + t] = f2bf(y);
}

// ---------------------------------------------------------------------------
// Head: out = tanh(y2 @ Wp3 + bp3) * scale + bias. 8 rows x 32 cols per block.
// ---------------------------------------------------------------------------
__global__ __launch_bounds__(256) void head_kernel(
    const u16* __restrict__ y2, const float* __restrict__ W,
    const float* __restrict__ bias, const float* __restrict__ scl,
    const float* __restrict__ bs, float* __restrict__ out)
{
    __shared__ float Ws[128 * ACT_];
    __shared__ u16 Ys[8 * 128];
    int t = threadIdx.x;
    for (int i = t; i < 128 * ACT_; i += 256) Ws[i] = W[i];
    int r0 = blockIdx.x * 8;
    for (int i = t; i < 8 * 128; i += 256) Ys[i] = y2[(size_t)r0 * 128 + i];
    __syncthreads();
    int lr = t >> 5, c = t & 31;
    if (c < ACT_) {
        float acc = bias[c];
        for (int kk = 0; kk < 128; kk++)
            acc += bf2f(Ys[lr * 128 + kk]) * Ws[kk * ACT_ + c];
        float y = tanhf(acc);
        out[(size_t)(r0 + lr) * ACT_ + c] = y * scl[c] + bs[c];
    }
}

// ---------------------------------------------------------------------------
extern "C" void kernel_launch(void* const* d_in, const int* in_sizes, int n_in,
                              void* d_out, int out_size, void* d_ws, size_t ws_size,
                              hipStream_t stream)
{
    const float* obs   = (const float*)d_in[0];
    const float* W_in  = (const float*)d_in[1];
    const float* b_in  = (const float*)d_in[2];
    const float* g_in  = (const float*)d_in[3];
    const float* be_in = (const float*)d_in[4];
    const float* Wq  = (const float*)d_in[5];
    const float* bq  = (const float*)d_in[6];
    const float* Wk  = (const float*)d_in[7];
    const float* bk  = (const float*)d_in[8];
    const float* Wv  = (const float*)d_in[9];
    const float* bv  = (const float*)d_in[10];
    const float* Wo  = (const float*)d_in[11];
    const float* bo  = (const float*)d_in[12];
    const float* g1  = (const float*)d_in[13];
    const float* be1 = (const float*)d_in[14];
    const float* W1  = (const float*)d_in[15];
    const float* b1  = (const float*)d_in[16];
    const float* W2  = (const float*)d_in[17];
    const float* b2  = (const float*)d_in[18];
    const float* g2  = (const float*)d_in[19];
    const float* be2 = (const float*)d_in[20];
    const float* Wp1  = (const float*)d_in[21];
    const float* bp1  = (const float*)d_in[22];
    const float* gp1  = (const float*)d_in[23];
    const float* bep1 = (const float*)d_in[24];
    const float* Wp2  = (const float*)d_in[25];
    const float* bp2  = (const float*)d_in[26];
    const float* gp2  = (const float*)d_in[27];
    const float* bep2 = (const float*)d_in[28];
    const float* Wp3  = (const float*)d_in[29];
    const float* bp3  = (const float*)d_in[30];
    const float* ascl = (const float*)d_in[31];
    const float* abias = (const float*)d_in[32];

    char* ws = (char*)d_ws;
    size_t off = 0;
    auto alloc = [&](size_t bytes) {
        void* p = ws + off;
        off += (bytes + 255) & ~(size_t)255;
        return p;
    };
    u16* WQKVT = (u16*)alloc((size_t)L_ * QKV3 * D_ * 2);     // 12.6 MB
    u16* WOT   = (u16*)alloc((size_t)L_ * D_ * D_ * 2);       // 4 MB
    u16* W1T   = (u16*)alloc((size_t)L_ * D_ * FF_ * 2);      // 16 MB
    u16* W2T   = (u16*)alloc((size_t)L_ * FF_ * D_ * 2);      // 16 MB
    u16* WP1T  = (u16*)alloc((size_t)D_ * (D_ / 2) * 2);
    u16* WP2T  = (u16*)alloc((size_t)(D_ / 2) * (D_ / 4) * 2);
    float* bqkv = (float*)alloc((size_t)L_ * QKV3 * 4);
    u16* x_bf = (u16*)alloc((size_t)NTOK * D_ * 2);           // 16 MB
    float* tmp = (float*)alloc((size_t)NTOK * D_ * 4);        // 32 MB (f32 or f16 use)
    char* regionA = (char*)alloc((size_t)NTOK * FF_ * 2);     // 64 MB
    size_t base_need = off;
    char* tmp2 = ws + base_need;                              // +16 MB if fits
    bool split = (ws_size >= base_need + (size_t)NTOK * D_ * 2);
    (void)in_sizes; (void)n_in; (void)out_size;

    u16* qkvbuf = (u16*)(regionA);                            // 48 MB
    u16* obuf = (u16*)(regionA + (size_t)NTOK * QKV3 * 2);    // 16 MB
    u16* hbuf = (u16*)(regionA);                              // 64 MB (aliases)
    // head-phase aliases (regionA free then)
    u16* y1_bf = (u16*)(regionA);                             // 8 MB
    u16* y2_bf = (u16*)(regionA + (32u << 20));               // 4 MB

    dim3 tb(32, 8);
    size_t DD = (size_t)D_ * D_;
    transpose_bf16_kernel<<<dim3(16, 16, L_), tb, 0, stream>>>(
        Wq, WQKVT, D_, D_, DD, (size_t)QKV3 * D_);
    transpose_bf16_kernel<<<dim3(16, 16, L_), tb, 0, stream>>>(
        Wk, WQKVT + DD, D_, D_, DD, (size_t)QKV3 * D_);
    transpose_bf16_kernel<<<dim3(16, 16, L_), tb, 0, stream>>>(
        Wv, WQKVT + 2 * DD, D_, D_, DD, (size_t)QKV3 * D_);
    transpose_bf16_kernel<<<dim3(16, 16, L_), tb, 0, stream>>>(
        Wo, WOT, D_, D_, DD, DD);
    transpose_bf16_kernel<<<dim3(64, 16, L_), tb, 0, stream>>>(
        W1, W1T, D_, FF_, (size_t)D_ * FF_, (size_t)D_ * FF_);
    transpose_bf16_kernel<<<dim3(16, 64, L_), tb, 0, stream>>>(
        W2, W2T, FF_, D_, (size_t)D_ * FF_, (size_t)D_ * FF_);
    transpose_bf16_kernel<<<dim3(8, 16, 1), tb, 0, stream>>>(
        Wp1, WP1T, D_, D_ / 2, 0, 0);
    transpose_bf16_kernel<<<dim3(4, 8, 1), tb, 0, stream>>>(
        Wp2, WP2T, D_ / 2, D_ / 4, 0, 0);
    concat_bias_kernel<<<L_ * QKV3 / 256, 256, 0, stream>>>(bq, bk, bv, bqkv);

    in_gemm_kernel<<<dim3(D_ / 64, NTOK / 64), 256, 0, stream>>>(
        obs, W_in, b_in, tmp);
    ln_kernel<D_, 0, false, true, true, false><<<NTOK, D_, 0, stream>>>(
        tmp, nullptr, nullptr, g_in, be_in, x_bf);

    const int MG = NTOK / 128;  // 128 M-blocks; grid = 128 * NX (y-fast)
    for (int l = 0; l < L_; l++) {
        const u16* wqkvt = WQKVT + (size_t)l * QKV3 * D_;
        const u16* wot = WOT + (size_t)l * DD;
        const u16* w1t = W1T + (size_t)l * D_ * FF_;
        const u16* w2t = W2T + (size_t)l * FF_ * D_;

        gemm_bt_kernel<0, 128, false><<<MG * (QKV3 / 128), 256, 0, stream>>>(
            x_bf, wqkvt, bqkv + l * QKV3, qkvbuf, nullptr, NTOK, QKV3, D_, D_);
        attn_kernel<<<B_ * H_ * (S_ / 64), 256, 0, stream>>>(qkvbuf, obuf);
        if (split) {
            gemm_bt_kernel<3, 128, true><<<dim3(MG * 4, 1, 2), 256, 0, stream>>>(
                obuf, wot, bo + l * D_, tmp, tmp2, NTOK, D_, D_, D_ / 2);
            ln_kernel<D_, 1, true, false, false, true><<<NTOK, D_, 0, stream>>>(
                tmp, tmp2, x_bf, g1 + l * D_, be1 + l * D_, x_bf);
        } else {
            gemm_bt_kernel<2, 128, false><<<MG * 4, 256, 0, stream>>>(
                obuf, wot, bo + l * D_, tmp, nullptr, NTOK, D_, D_, D_);
            ln_kernel<D_, 0, true, false, false, false><<<NTOK, D_, 0, stream>>>(
                tmp, nullptr, x_bf, g1 + l * D_, be1 + l * D_, x_bf);
        }
        gemm_bt_kernel<1, 128, false><<<MG * (FF_ / 128), 256, 0, stream>>>(
            x_bf, w1t, b1 + l * FF_, hbuf, nullptr, NTOK, FF_, D_, D_);
        if (split) {
            gemm_bt_kernel<3, 128, true><<<dim3(MG * 4, 1, 2), 256, 0, stream>>>(
                hbuf, w2t, b2 + l * D_, tmp, tmp2, NTOK, D_, FF_, FF_ / 2);
            ln_kernel<D_, 1, true, false, false, true><<<NTOK, D_, 0, stream>>>(
                tmp, tmp2, x_bf, g2 + l * D_, be2 + l * D_, x_bf);
        } else {
            gemm_bt_kernel<2, 128, false><<<MG * 4, 256, 0, stream>>>(
                hbuf, w2t, b2 + l * D_, tmp, nullptr, NTOK, D_, FF_, FF_);
            ln_kernel<D_, 0, true, false, false, false><<<NTOK, D_, 0, stream>>>(
                tmp, nullptr, x_bf, g2 + l * D_, be2 + l * D_, x_bf);
        }
    }

    // policy head
    if (split) {
        gemm_bt_kernel<3, 64, true><<<dim3(MG * 4, 1, 2), 256, 0, stream>>>(
            x_bf, WP1T, bp1, tmp, tmp2, NTOK, D_ / 2, D_, D_ / 2);
        ln_kernel<D_ / 2, 1, false, true, false, true><<<NTOK, D_ / 2, 0, stream>>>(
            tmp, tmp2, nullptr, gp1, bep1, y1_bf);
        gemm_bt_kernel<3, 64, true><<<dim3(MG * 2, 1, 2), 256, 0, stream>>>(
            y1_bf, WP2T, bp2, tmp, tmp2, NTOK, D_ / 4, D_ / 2, D_ / 4);
        ln_kernel<D_ / 4, 1, false, true, false, true><<<NTOK, D_ / 4, 0, stream>>>(
            tmp, tmp2, nullptr, gp2, bep2, y2_bf);
    } else {
        gemm_bt_kernel<2, 64, false><<<MG * 4, 256, 0, stream>>>(
            x_bf, WP1T, bp1, tmp, nullptr, NTOK, D_ / 2, D_, D_);
        ln_kernel<D_ / 2, 0, false, true, false, false><<<NTOK, D_ / 2, 0, stream>>>(
            tmp, nullptr, nullptr, gp1, bep1, y1_bf);
        gemm_bt_kernel<2, 64, false><<<MG * 2, 256, 0, stream>>>(
            y1_bf, WP2T, bp2, tmp, nullptr, NTOK, D_ / 4, D_ / 2, D_ / 2);
        ln_kernel<D_ / 4, 0, false, true, false, false><<<NTOK, D_ / 4, 0, stream>>>(
            tmp, nullptr, nullptr, gp2, bep2, y2_bf);
    }
    head_kernel<<<NTOK / 8, 256, 0, stream>>>(
        y2_bf, Wp3, bp3, ascl, abias, (float*)d_out);
}